// Round 13
// baseline (687.601 us; speedup 1.0000x reference)
//
#include <hip/hip_runtime.h>
#include <math.h>

#define NB 256
#define LL 512
#define CIN 514

__device__ __forceinline__ float lrelu(float x) { return x >= 0.f ? x : 0.2f * x; }

// ---------------- positional encoding table [128][512], fp64 math like numpy ----------------
__global__ __launch_bounds__(256) void k_pos(float* __restrict__ pos) {
    int idx = blockIdx.x * 256 + threadIdx.x;   // 65536 total
    int c = idx >> 9, l = idx & 511;
    double e = (double)(2 * (c >> 1)) / 128.0;
    double dv = 1.0 / pow(10000.0, e);
    double a = (double)l * dv;
    pos[idx] = (float)((c & 1) ? cos(a) : sin(a));
}

// ---------------- posconv: PC[o][l] = bias[o] + sum_c sum_k W[o][c][k]*POS[c][l+k-3] ----------------
__global__ __launch_bounds__(256) void k_posconv(const float* __restrict__ POS, const float* __restrict__ W,
                                                 const float* __restrict__ bias, float* __restrict__ PC) {
    const int t = threadIdx.x;
    const int o = blockIdx.x >> 4, l0 = (blockIdx.x & 15) * 32;
    const int l = l0 + (t & 31), cs = t >> 5;
    float acc = 0.f;
    for (int ci = 0; ci < 16; ++ci) {
        int c = cs * 16 + ci;
        float wv[7];
#pragma unroll
        for (int k = 0; k < 7; ++k) wv[k] = W[o * 896 + c * 7 + k];
#pragma unroll
        for (int k = 0; k < 7; ++k) {
            int gl = l + k - 3;
            if (gl >= 0 && gl < LL) acc += wv[k] * POS[c * LL + gl];
        }
    }
    __shared__ float red[8][33];
    red[cs][t & 31] = acc;
    __syncthreads();
    if (cs == 0) {
        float s = bias[o];
#pragma unroll
        for (int j = 0; j < 8; ++j) s += red[j][t & 31];
        PC[o * LL + l0 + (t & 31)] = s;
    }
}

// ---------------- conv1 v5: 1x1, 514->32, K-split z=4, direct LDS staging (low VGPR) ----------------
// grid 1024: n = b>>2, z = b&3. Block: 512 l x 32 o, K-quarter (128/130).
__global__ __launch_bounds__(256) void k_conv1(const float* __restrict__ X, const float* __restrict__ W,
                                               float* __restrict__ Pbase) {
    __shared__ __align__(16) float As[16][524];   // [kk][l]
    __shared__ __align__(16) float Bs[16][36];    // [kk][o]
    const int t = threadIdx.x;
    const int n = blockIdx.x >> 2, z = blockIdx.x & 3;
    const int kbase = z * 128;
    const int nch = (z == 3) ? 9 : 8;
    const int tl = t & 63, to = t >> 6;
    const size_t rowbase = (size_t)n * 512 * CIN;

    float acc[8][8];
#pragma unroll
    for (int oi = 0; oi < 8; ++oi)
#pragma unroll
        for (int p = 0; p < 8; ++p) acc[oi][p] = 0.f;

    for (int c = 0; c < nch; ++c) {
        const int kb = kbase + c * 16;
        if (c) __syncthreads();
        // stage A: idx = ps*256+t -> pos = idx>>3 (0..511), kpair = idx&7
#pragma unroll
        for (int ps = 0; ps < 16; ++ps) {
            int idx = ps * 256 + t;
            int pos = idx >> 3, kp = idx & 7;
            int gk = kb + kp * 2;
            float2 v = {0.f, 0.f};
            if (gk + 1 < CIN) v = *(const float2*)(X + rowbase + (size_t)pos * CIN + gk);
            else if (gk < CIN) v.x = X[rowbase + (size_t)pos * CIN + gk];
            As[kp * 2][pos] = v.x;
            As[kp * 2 + 1][pos] = v.y;
        }
        {
            int o = t >> 3, kp = t & 7;
            int gk = kb + kp * 2;
            float2 v = {0.f, 0.f};
            if (gk + 1 < CIN) v = *(const float2*)(W + (size_t)o * CIN + gk);
            else if (gk < CIN) v.x = W[(size_t)o * CIN + gk];
            Bs[kp * 2][o] = v.x;
            Bs[kp * 2 + 1][o] = v.y;
        }
        __syncthreads();
#pragma unroll
        for (int kk = 0; kk < 16; ++kk) {
            float4 aL = *(const float4*)&As[kk][tl * 4];
            float4 aH = *(const float4*)&As[kk][256 + tl * 4];
            float4 b0 = *(const float4*)&Bs[kk][to * 8];
            float4 b1 = *(const float4*)&Bs[kk][to * 8 + 4];
            float av[8] = {aL.x, aL.y, aL.z, aL.w, aH.x, aH.y, aH.z, aH.w};
            float bv[8] = {b0.x, b0.y, b0.z, b0.w, b1.x, b1.y, b1.z, b1.w};
#pragma unroll
            for (int oi = 0; oi < 8; ++oi)
#pragma unroll
                for (int p = 0; p < 8; ++p) acc[oi][p] += av[p] * bv[oi];
        }
    }

    float* P = Pbase + (size_t)z * 4194304;
#pragma unroll
    for (int oi = 0; oi < 8; ++oi) {
        int o = to * 8 + oi;
        float4 v0 = {acc[oi][0], acc[oi][1], acc[oi][2], acc[oi][3]};
        float4 v1 = {acc[oi][4], acc[oi][5], acc[oi][6], acc[oi][7]};
        *(float4*)(P + ((size_t)n * 32 + o) * LL + tl * 4) = v0;
        *(float4*)(P + ((size_t)n * 32 + o) * LL + 256 + tl * 4) = v1;
    }
}

// ---------------- conv2: k=3 pad=1, 32->16, + bias. Input = lrelu(P0..P3+b1) fused; emits BN partials ----------------
__global__ __launch_bounds__(256) void k_conv2(const float* __restrict__ Pbase,
                                               const float* __restrict__ b1, const float* __restrict__ W,
                                               const float* __restrict__ bias, float* __restrict__ out,
                                               float* __restrict__ part) {
    __shared__ __align__(16) float Xs[32][264];
    __shared__ __align__(16) float Ws[16][32][4];
    __shared__ float reds[16][33], redq[16][33];
    const int t = threadIdx.x;
    const int bid = blockIdx.x;
    const int n = bid >> 1, l0 = (bid & 1) * 256;
    for (int idx = t; idx < 32 * 258; idx += 256) {
        int i = idx / 258, j = idx % 258;
        int gl = l0 - 1 + j;
        float v = 0.f;
        if (gl >= 0 && gl < LL) {
            size_t off = ((size_t)n * 32 + i) * LL + gl;
            v = lrelu(Pbase[off] + Pbase[off + 4194304] + Pbase[off + 8388608] + Pbase[off + 12582912] + b1[i]);
        }
        Xs[i][j] = v;
    }
    for (int idx = t; idx < 1536; idx += 256) {
        int o = idx / 96, r = idx % 96;
        Ws[o][r / 3][r % 3] = W[idx];
    }
    __syncthreads();
    const int tx = t & 31, ty = t >> 5;
    float acc[2][8];
#pragma unroll
    for (int q = 0; q < 2; ++q)
#pragma unroll
        for (int p = 0; p < 8; ++p) acc[q][p] = 0.f;
    for (int i = 0; i < 32; ++i) {
        float4 a0 = *(const float4*)&Xs[i][tx*8];
        float4 a1 = *(const float4*)&Xs[i][tx*8+4];
        float4 a2 = *(const float4*)&Xs[i][tx*8+8];
        float a[12] = {a0.x,a0.y,a0.z,a0.w,a1.x,a1.y,a1.z,a1.w,a2.x,a2.y,a2.z,a2.w};
#pragma unroll
        for (int q = 0; q < 2; ++q) {
            float4 b = *(const float4*)&Ws[ty*2+q][i][0];
#pragma unroll
            for (int p = 0; p < 8; ++p)
                acc[q][p] += a[p]*b.x + a[p+1]*b.y + a[p+2]*b.z;
        }
    }
#pragma unroll
    for (int q = 0; q < 2; ++q) {
        int o = ty*2+q; float bb = bias[o];
        float s = 0.f, sq = 0.f;
#pragma unroll
        for (int h = 0; h < 2; ++h) {
            float4 v;
            v.x = acc[q][h*4+0] + bb; v.y = acc[q][h*4+1] + bb;
            v.z = acc[q][h*4+2] + bb; v.w = acc[q][h*4+3] + bb;
            s += v.x + v.y + v.z + v.w;
            sq += v.x*v.x + v.y*v.y + v.z*v.z + v.w*v.w;
            *(float4*)(out + ((size_t)n*16 + o)*LL + l0 + tx*8 + h*4) = v;
        }
        reds[o][tx] = s;
        redq[o][tx] = sq;
    }
    __syncthreads();
    if (t < 16) {
        float s = 0.f, sq = 0.f;
#pragma unroll
        for (int x = 0; x < 32; ++x) { s += reds[t][x]; sq += redq[t][x]; }
        part[((size_t)t * 512 + bid) * 2] = s;
        part[((size_t)t * 512 + bid) * 2 + 1] = sq;
    }
}

// ---------------- BN final: reduce S slices per channel ----------------
__global__ void k_bnfinal(const float* __restrict__ part, const float* __restrict__ g,
                          const float* __restrict__ b, int C, int S, float* __restrict__ ss) {
    int ch = threadIdx.x;
    if (ch >= C) return;
    float s = 0.f, q = 0.f;
    for (int j = 0; j < S; ++j) { s += part[((size_t)ch*S + j)*2]; q += part[((size_t)ch*S + j)*2 + 1]; }
    float mean = s * (1.f/131072.f);
    float var = q * (1.f/131072.f) - mean*mean;
    float sc = g[ch] / sqrtf(var + 1e-5f);
    ss[ch] = sc;
    ss[C + ch] = b[ch] - mean * sc;
}

__global__ __launch_bounds__(256) void k_bnapply(const float* __restrict__ src, const float* __restrict__ ss,
        int C, float* __restrict__ dst, int act, int total4) {
    int i4 = blockIdx.x * 256 + threadIdx.x;
    if (i4 >= total4) return;
    int i = i4 << 2;
    int ch = (i >> 9) % C;
    float sc = ss[ch], sh = ss[C + ch];
    float4 v = reinterpret_cast<const float4*>(src)[i4];
    v.x = v.x*sc + sh; v.y = v.y*sc + sh; v.z = v.z*sc + sh; v.w = v.w*sc + sh;
    if (act) { v.x = lrelu(v.x); v.y = lrelu(v.y); v.z = lrelu(v.z); v.w = lrelu(v.w); }
    reinterpret_cast<float4*>(dst)[i4] = v;
}

// ---------------- m_conv1 v6: k=7 pad=3, 128->32. K-split x2, 8 half-stages, LDS dbuf, coalesced NZ staging ----------------
__global__ __launch_bounds__(256) void k_mconv1(const float* __restrict__ C16, const float* __restrict__ NZ,
        const float* __restrict__ PC, const float* __restrict__ W,
        float* __restrict__ out0, float* __restrict__ out1) {
    __shared__ __align__(16) float Gs[2][8][268];
    __shared__ __align__(16) float Ws[2][32][8][8];
    const int t = threadIdx.x;
    const int n = blockIdx.x >> 2, l0 = ((blockIdx.x >> 1) & 1) * 256, z = blockIdx.x & 1;
    const int tx = t & 31, ty = t >> 5;
    float acc[4][8];
#pragma unroll
    for (int q = 0; q < 4; ++q)
#pragma unroll
        for (int p = 0; p < 8; ++p) acc[q][p] = 0.f;

    float4 ga0, ga1, gb0, gb1;
    float wpf[8];
    const int gl1 = l0 - 3 + t;
    const bool ok1 = (gl1 >= 0 && gl1 < LL);
    const int gl2 = l0 + 253 + t;
    const bool ok2 = (t < 6) && (gl2 < LL);

    auto LOADG = [&](int hh) {
        const float4 f4z = {0.f, 0.f, 0.f, 0.f};
        ga0 = f4z; ga1 = f4z; gb0 = f4z; gb1 = f4z;
        if (z == 0 && hh < 2) {
            const float* base = C16 + ((size_t)n * 16 + hh * 8) * LL;
            if (ok1) {
                const float* p = base + gl1;
                ga0.x = p[0];      ga0.y = p[LL];     ga0.z = p[2*LL];  ga0.w = p[3*LL];
                ga1.x = p[4*LL];   ga1.y = p[5*LL];   ga1.z = p[6*LL];  ga1.w = p[7*LL];
            }
            if (ok2) {
                const float* p = base + gl2;
                gb0.x = p[0];      gb0.y = p[LL];     gb0.z = p[2*LL];  gb0.w = p[3*LL];
                gb1.x = p[4*LL];   gb1.y = p[5*LL];   gb1.z = p[6*LL];  gb1.w = p[7*LL];
            }
        } else {
            const int nzc = z * 64 + hh * 8 - 16;
            if (ok1) {
                const float* p = NZ + ((size_t)n * LL + gl1) * 112 + nzc;
                ga0 = *(const float4*)p;
                ga1 = *(const float4*)(p + 4);
            }
            if (ok2) {
                const float* p = NZ + ((size_t)n * LL + gl2) * 112 + nzc;
                gb0 = *(const float4*)p;
                gb1 = *(const float4*)(p + 4);
            }
        }
    };
    auto WRITEG = [&](int bb) {
        Gs[bb][0][t] = ga0.x; Gs[bb][1][t] = ga0.y; Gs[bb][2][t] = ga0.z; Gs[bb][3][t] = ga0.w;
        Gs[bb][4][t] = ga1.x; Gs[bb][5][t] = ga1.y; Gs[bb][6][t] = ga1.z; Gs[bb][7][t] = ga1.w;
        if (t < 6) {
            Gs[bb][0][256+t] = gb0.x; Gs[bb][1][256+t] = gb0.y; Gs[bb][2][256+t] = gb0.z; Gs[bb][3][256+t] = gb0.w;
            Gs[bb][4][256+t] = gb1.x; Gs[bb][5][256+t] = gb1.y; Gs[bb][6][256+t] = gb1.z; Gs[bb][7][256+t] = gb1.w;
        }
    };
    auto LOADW = [&](int hh) {
        const int b7 = (z * 64 + hh * 8) * 7;
#pragma unroll
        for (int p = 0; p < 8; ++p) {
            int idx = p * 256 + t;
            int k = idx & 7, ci = (idx >> 3) & 7, o = idx >> 6;
            wpf[p] = (k < 7) ? W[(size_t)o * 896 + b7 + ci * 7 + k] : 0.f;
        }
    };
    auto WRITEW = [&](int bb) {
#pragma unroll
        for (int p = 0; p < 8; ++p) {
            int idx = p * 256 + t;
            int k = idx & 7;
            if (k < 7) {
                int ci = (idx >> 3) & 7, o = idx >> 6;
                Ws[bb][o][ci][k] = wpf[p];
            }
        }
    };

    LOADG(0);
    LOADW(0);
    WRITEG(0);
    WRITEW(0);
    __syncthreads();

    for (int h = 0; h < 8; ++h) {
        const int hb = h & 1;
        if (h < 7) {
            LOADG(h + 1);
            LOADW(h + 1);
        }
        for (int ci = 0; ci < 8; ++ci) {
            float4 a0 = *(const float4*)&Gs[hb][ci][tx*4];
            float4 a1 = *(const float4*)&Gs[hb][ci][tx*4+4];
            float4 a2 = *(const float4*)&Gs[hb][ci][tx*4+8];
            float4 a3 = *(const float4*)&Gs[hb][ci][128+tx*4];
            float4 a4 = *(const float4*)&Gs[hb][ci][128+tx*4+4];
            float4 a5 = *(const float4*)&Gs[hb][ci][128+tx*4+8];
            float aA[12] = {a0.x,a0.y,a0.z,a0.w,a1.x,a1.y,a1.z,a1.w,a2.x,a2.y,a2.z,a2.w};
            float aB[12] = {a3.x,a3.y,a3.z,a3.w,a4.x,a4.y,a4.z,a4.w,a5.x,a5.y,a5.z,a5.w};
#pragma unroll
            for (int q = 0; q < 4; ++q) {
                float4 b0 = *(const float4*)&Ws[hb][ty*4+q][ci][0];
                float4 b1 = *(const float4*)&Ws[hb][ty*4+q][ci][4];
                float b[7] = {b0.x,b0.y,b0.z,b0.w,b1.x,b1.y,b1.z};
#pragma unroll
                for (int p = 0; p < 4; ++p) {
#pragma unroll
                    for (int k = 0; k < 7; ++k) {
                        acc[q][p]   += aA[p+k]*b[k];
                        acc[q][4+p] += aB[p+k]*b[k];
                    }
                }
            }
        }
        if (h < 7) {
            const int nb = hb ^ 1;
            WRITEG(nb);
            WRITEW(nb);
            __syncthreads();
        }
    }

    float* out = z ? out1 : out0;
#pragma unroll
    for (int q = 0; q < 4; ++q) {
        int o = ty*4 + q;
        float4 p0 = {0.f,0.f,0.f,0.f}, p1 = {0.f,0.f,0.f,0.f};
        if (z == 0) {
            p0 = *(const float4*)(PC + o*LL + l0 + tx*4);
            p1 = *(const float4*)(PC + o*LL + l0 + 128 + tx*4);
        }
        float4 v0 = {acc[q][0]+p0.x, acc[q][1]+p0.y, acc[q][2]+p0.z, acc[q][3]+p0.w};
        float4 v1 = {acc[q][4]+p1.x, acc[q][5]+p1.y, acc[q][6]+p1.z, acc[q][7]+p1.w};
        *(float4*)(out + ((size_t)n*32 + o)*LL + l0 + tx*4) = v0;
        *(float4*)(out + ((size_t)n*32 + o)*LL + l0 + 128 + tx*4) = v1;
    }
}

// ---------------- m_conv2: k=3 pad=1, 32->8, + bias. Input = lrelu(P0+P1) fused; emits BN partials ----------------
__global__ __launch_bounds__(256) void k_mconv2(const float* __restrict__ P0, const float* __restrict__ P1,
        const float* __restrict__ W, const float* __restrict__ bias, float* __restrict__ out,
        float* __restrict__ part) {
    __shared__ __align__(16) float Xs[32][264];
    __shared__ __align__(16) float Ws[8][32][4];
    __shared__ float reds[8][33], redq[8][33];
    const int t = threadIdx.x;
    const int bid = blockIdx.x;
    const int n = bid >> 1, l0 = (bid & 1) * 256;
    for (int idx = t; idx < 32 * 258; idx += 256) {
        int i = idx / 258, j = idx % 258;
        int gl = l0 - 1 + j;
        float v = 0.f;
        if (gl >= 0 && gl < LL) {
            size_t off = ((size_t)n * 32 + i) * LL + gl;
            v = lrelu(P0[off] + P1[off]);
        }
        Xs[i][j] = v;
    }
    for (int idx = t; idx < 768; idx += 256) {
        int o = idx / 96, r = idx % 96;
        Ws[o][r / 3][r % 3] = W[idx];
    }
    __syncthreads();
    const int tx = t & 31, ty = t >> 5;
    float acc[8];
#pragma unroll
    for (int p = 0; p < 8; ++p) acc[p] = 0.f;
    for (int i = 0; i < 32; ++i) {
        float4 a0 = *(const float4*)&Xs[i][tx*8];
        float4 a1 = *(const float4*)&Xs[i][tx*8+4];
        float4 a2 = *(const float4*)&Xs[i][tx*8+8];
        float a[12] = {a0.x,a0.y,a0.z,a0.w,a1.x,a1.y,a1.z,a1.w,a2.x,a2.y,a2.z,a2.w};
        float4 b = *(const float4*)&Ws[ty][i][0];
#pragma unroll
        for (int p = 0; p < 8; ++p)
            acc[p] += a[p]*b.x + a[p+1]*b.y + a[p+2]*b.z;
    }
    float bb = bias[ty];
    float s = 0.f, sq = 0.f;
#pragma unroll
    for (int h = 0; h < 2; ++h) {
        float4 v;
        v.x = acc[h*4+0] + bb; v.y = acc[h*4+1] + bb;
        v.z = acc[h*4+2] + bb; v.w = acc[h*4+3] + bb;
        s += v.x + v.y + v.z + v.w;
        sq += v.x*v.x + v.y*v.y + v.z*v.z + v.w*v.w;
        *(float4*)(out + ((size_t)n*8 + ty)*LL + l0 + tx*8 + h*4) = v;
    }
    reds[ty][tx] = s;
    redq[ty][tx] = sq;
    __syncthreads();
    if (t < 8) {
        float ss = 0.f, qq = 0.f;
#pragma unroll
        for (int x = 0; x < 32; ++x) { ss += reds[t][x]; qq += redq[t][x]; }
        part[((size_t)t * 512 + bid) * 2] = ss;
        part[((size_t)t * 512 + bid) * 2 + 1] = qq;
    }
}

// ---------------- linear 4096x4096 v4: 128x128 tile, BK=16, 8x8 micro, z=16, no prefetch ----------------
__global__ __launch_bounds__(256) void k_lin(const float* __restrict__ A, const float* __restrict__ B,
                                             float* __restrict__ part) {
    __shared__ __align__(16) float As[16][132];
    __shared__ __align__(16) float Bs[16][132];
    const int t = threadIdx.x;
    const int bid = blockIdx.x;
    const int xcd = bid & 7, j = bid >> 3;
    const int z = j >> 3;
    const int m0 = ((j >> 2) & 1) * 128;
    const int f0 = (xcd * 4 + (j & 3)) * 128;
    const int k0base = z * 256;
    const int sar = t & 127, saq = t >> 7;
    const int sbr = t >> 4, sbq = t & 15;
    const int mq = (t & 15) * 4, fq = (t >> 4) * 4;

    float acc[8][8];
#pragma unroll
    for (int i = 0; i < 8; ++i)
#pragma unroll
        for (int q = 0; q < 8; ++q) acc[i][q] = 0.f;

    for (int it = 0; it < 16; ++it) {
        const int k0 = k0base + it * 16;
        {
            const float* pA = A + (size_t)(m0 + sar) * 4096 + k0 + saq * 8;
            float4 a0 = *(const float4*)(pA);
            float4 a1 = *(const float4*)(pA + 4);
            const float* pB = B + (size_t)(k0 + sbr) * 4096 + f0 + sbq * 8;
            float4 b0 = *(const float4*)(pB);
            float4 b1 = *(const float4*)(pB + 4);
            As[saq*8+0][sar] = a0.x; As[saq*8+1][sar] = a0.y; As[saq*8+2][sar] = a0.z; As[saq*8+3][sar] = a0.w;
            As[saq*8+4][sar] = a1.x; As[saq*8+5][sar] = a1.y; As[saq*8+6][sar] = a1.z; As[saq*8+7][sar] = a1.w;
            *(float4*)&Bs[sbr][sbq*8] = b0;
            *(float4*)&Bs[sbr][sbq*8+4] = b1;
        }
        __syncthreads();
#pragma unroll
        for (int kk = 0; kk < 16; ++kk) {
            float4 a0 = *(const float4*)&As[kk][mq];
            float4 a1 = *(const float4*)&As[kk][mq + 64];
            float4 b0 = *(const float4*)&Bs[kk][fq];
            float4 b1 = *(const float4*)&Bs[kk][fq + 64];
            float av[8] = {a0.x,a0.y,a0.z,a0.w,a1.x,a1.y,a1.z,a1.w};
            float bv[8] = {b0.x,b0.y,b0.z,b0.w,b1.x,b1.y,b1.z,b1.w};
#pragma unroll
            for (int i = 0; i < 8; ++i)
#pragma unroll
                for (int q = 0; q < 8; ++q) acc[i][q] += av[i] * bv[q];
        }
        __syncthreads();
    }

#pragma unroll
    for (int i = 0; i < 8; ++i) {
        int m = m0 + mq + (i & 3) + (i >> 2) * 64;
        float4 v0 = {acc[i][0], acc[i][1], acc[i][2], acc[i][3]};
        float4 v1 = {acc[i][4], acc[i][5], acc[i][6], acc[i][7]};
        *(float4*)(part + ((size_t)z * 256 + m) * 4096 + f0 + fq) = v0;
        *(float4*)(part + ((size_t)z * 256 + m) * 4096 + f0 + fq + 64) = v1;
    }
}

// sum 16 K-partials + bias + lrelu
__global__ __launch_bounds__(256) void k_linred(const float* __restrict__ part, const float* __restrict__ bias,
        float* __restrict__ out) {
    int i4 = blockIdx.x*256 + threadIdx.x;   // < 262144
    int i = i4 << 2;
    int f = i & 4095;
    float4 s = *(const float4*)(bias + f);
#pragma unroll
    for (int zz = 0; zz < 16; ++zz) {
        float4 p = ((const float4*)(part + (size_t)zz * 1048576))[i4];
        s.x += p.x; s.y += p.y; s.z += p.z; s.w += p.w;
    }
    float4 r;
    r.x = lrelu(s.x); r.y = lrelu(s.y); r.z = lrelu(s.z); r.w = lrelu(s.w);
    ((float4*)out)[i4] = r;
}

// ---------------- heads: [4096x512 | 4096x256], split-K (16), no prefetch ----------------
__global__ __launch_bounds__(256) void k_heads(const float* __restrict__ A, const float* __restrict__ CW,
        const float* __restrict__ SW, float* __restrict__ part) {
    __shared__ __align__(16) float As[32][36];
    __shared__ __align__(16) float Bs[32][132];
    const int t = threadIdx.x;
    const int m0 = blockIdx.x * 32, f0 = blockIdx.y * 128, z = blockIdx.z;
    const float* B; int ldb, fb;
    if (f0 < 512) { B = CW; ldb = 512; fb = f0; } else { B = SW; ldb = 256; fb = f0 - 512; }
    const int tm = t & 7, tf = t >> 3;
    const int mi = t >> 3, kq = t & 7;
    float acc[4][4];
#pragma unroll
    for (int pm = 0; pm < 4; ++pm)
#pragma unroll
        for (int pf = 0; pf < 4; ++pf) acc[pm][pf] = 0.f;
    for (int k0 = z * 256; k0 < z * 256 + 256; k0 += 32) {
        float4 av = *(const float4*)(A + (size_t)(m0 + mi) * 4096 + k0 + kq * 4);
        As[kq*4+0][mi] = av.x; As[kq*4+1][mi] = av.y; As[kq*4+2][mi] = av.z; As[kq*4+3][mi] = av.w;
#pragma unroll
        for (int pass = 0; pass < 4; ++pass) {
            int fi = pass * 32 + kq * 4;
            *(float4*)&Bs[mi][fi] = *(const float4*)(B + (size_t)(k0 + mi) * ldb + fb + fi);
        }
        __syncthreads();
#pragma unroll 8
        for (int kk = 0; kk < 32; ++kk) {
            float4 a = *(const float4*)&As[kk][tm * 4];
            float4 b = *(const float4*)&Bs[kk][tf * 4];
            float avv[4] = {a.x,a.y,a.z,a.w};
            float bvv[4] = {b.x,b.y,b.z,b.w};
#pragma unroll
            for (int pm = 0; pm < 4; ++pm)
#pragma unroll
                for (int pf = 0; pf < 4; ++pf) acc[pm][pf] += avv[pm]*bvv[pf];
        }
        __syncthreads();
    }
#pragma unroll
    for (int pm = 0; pm < 4; ++pm) {
        float4 v = {acc[pm][0], acc[pm][1], acc[pm][2], acc[pm][3]};
        *(float4*)(part + ((size_t)z * 256 + m0 + tm * 4 + pm) * 768 + f0 + tf * 4) = v;
    }
}

// ---------------- assemble (fused headred) + gumbel softmax(hard) ----------------
__global__ __launch_bounds__(256) void k_assemble(const float* __restrict__ part, const float* __restrict__ cb,
        const float* __restrict__ sb, const float* __restrict__ gum, float* __restrict__ out) {
    __shared__ float buf[768];
    const int n = blockIdx.x;
    const int t = threadIdx.x;
#pragma unroll
    for (int rep = 0; rep < 3; ++rep) {
        int f = rep * 256 + t;
        float s = 0.f;
#pragma unroll
        for (int ks = 0; ks < 16; ++ks) s += part[((size_t)(ks * 256 + n)) * 768 + f];
        s += (f < 512) ? cb[f] : sb[f - 512];
        buf[f] = s;
    }
    __syncthreads();
    if (t >= 128) return;
    const int b = t;
    const float* cp = buf;
    const float* sp = buf + 512;
    float sl0 = sp[2*b], sl1 = sp[2*b+1];
    int s = sl1 > sl0 ? 1 : 0;
    int prevb = 0;
    if (b > 0) prevb = (sp[2*b-1] > sp[2*b-2]) ? 1 : 0;
    bool body = (s == 1) && (b < 127);
    bool tail = ((s == 1) && (b == 127)) || ((s == 0) && (prevb == 1));
    float c0a = cp[4*b], c0b = cp[4*b+1], c1a = cp[4*b+2], c1b = cp[4*b+3];
    bool cA = c0b > c0a, cB = c1b > c1a;
    float rows[4][3];
    if (body || tail)      { rows[0][0]=sl0; rows[0][1]=0.f; rows[0][2]=sl1; }
    else if (cA)           { rows[0][0]=c0a; rows[0][1]=c0b; rows[0][2]=0.f; }
    else                   { rows[0][0]=1.f; rows[0][1]=0.f; rows[0][2]=0.f; }
    if (body)              { rows[1][0]=0.f; rows[1][1]=0.f; rows[1][2]=1.f; }
    else                   { rows[1][0]=1.f; rows[1][1]=0.f; rows[1][2]=0.f; }
    if (body)              { rows[2][0]=0.f; rows[2][1]=0.f; rows[2][2]=1.f; }
    else if (cB)           { rows[2][0]=c1a; rows[2][1]=c1b; rows[2][2]=0.f; }
    else                   { rows[2][0]=1.f; rows[2][1]=0.f; rows[2][2]=0.f; }
    rows[3][0]=rows[1][0]; rows[3][1]=rows[1][1]; rows[3][2]=rows[1][2];
#pragma unroll
    for (int r = 0; r < 4; ++r) {
        int l = 4*b + r;
        const float* u = gum + ((size_t)n*512 + l)*3;
        float g0 = -logf(-logf(u[0]+1e-10f)+1e-10f);
        float g1 = -logf(-logf(u[1]+1e-10f)+1e-10f);
        float g2 = -logf(-logf(u[2]+1e-10f)+1e-10f);
        float t0 = rows[r][0]+g0, t1 = rows[r][1]+g1, t2 = rows[r][2]+g2;
        int am = 0; float mv = t0;
        if (t1 > mv) { am = 1; mv = t1; }
        if (t2 > mv) { am = 2; mv = t2; }
        float e0 = expf(t0-mv), e1 = expf(t1-mv), e2 = expf(t2-mv);
        float ssum = e0+e1+e2;
        float y0 = e0/ssum, y1 = e1/ssum, y2 = e2/ssum;
        float* o = out + ((size_t)n*512 + l)*3;
        o[0] = ((am==0?1.f:0.f) + y0) - y0;
        o[1] = ((am==1?1.f:0.f) + y1) - y1;
        o[2] = ((am==2?1.f:0.f) + y2) - y2;
    }
}

extern "C" void kernel_launch(void* const* d_in, const int* in_sizes, int n_in,
                              void* d_out, int out_size, void* d_ws, size_t ws_size,
                              hipStream_t stream) {
    const float* noise   = (const float*)d_in[0];
    const float* cond    = (const float*)d_in[1];
    const float* gumbel  = (const float*)d_in[2];
    const float* ext_w1  = (const float*)d_in[3];
    const float* ext_b1  = (const float*)d_in[4];
    const float* ext_w2  = (const float*)d_in[5];
    const float* ext_b2  = (const float*)d_in[6];
    const float* ext_bng = (const float*)d_in[7];
    const float* ext_bnb = (const float*)d_in[8];
    const float* m_w1    = (const float*)d_in[9];
    const float* m_b1    = (const float*)d_in[10];
    const float* m_w2    = (const float*)d_in[11];
    const float* m_b2    = (const float*)d_in[12];
    const float* m_bng   = (const float*)d_in[13];
    const float* m_bnb   = (const float*)d_in[14];
    const float* lin_w   = (const float*)d_in[15];
    const float* lin_b   = (const float*)d_in[16];
    const float* circ_w  = (const float*)d_in[17];
    const float* circ_b  = (const float*)d_in[18];
    const float* slid_w  = (const float*)d_in[19];
    const float* slid_b  = (const float*)d_in[20];

    float* genout  = (float*)d_out;                       // [256][512][3]
    float* condout = (float*)d_out + 256*512*3;           // [256][16][512]

    float* w     = (float*)d_ws;
    float* ws0   = w;                  // 16,777,216 floats: conv1 partials z0-3 / mconv1 partials / k_lin partials
    float* y2    = ws0 + 16777216;     // 2097152 (h2 raw / flat_in)
    float* posb  = y2 + 2097152;       // 65536
    float* pc    = posb + 65536;       // 16384  (posconv table [32][512])
    float* flatB = pc + 16384;         // 1048576
    float* partH = flatB + 1048576;    // 3145728 (heads partials z=16)
    float* statA = partH + 3145728;    // 16384 (conv2 BN partials: 16ch x 512 x 2)
    float* ssA   = statA + 16384;      // 64
    float* statB = ssA + 64;           // 8192 (mconv2 BN partials: 8ch x 512 x 2)
    float* ssB   = statB + 8192;       // 64

    k_pos<<<256, 256, 0, stream>>>(posb);
    k_posconv<<<512, 256, 0, stream>>>(posb, m_w1, m_b1, pc);
    k_conv1<<<1024, 256, 0, stream>>>(cond, ext_w1, ws0);
    k_conv2<<<512, 256, 0, stream>>>(ws0, ext_b1, ext_w2, ext_b2, y2, statA);
    k_bnfinal<<<1, 64, 0, stream>>>(statA, ext_bng, ext_bnb, 16, 512, ssA);
    k_bnapply<<<2048, 256, 0, stream>>>(y2, ssA, 16, condout, 0, 524288);
    k_mconv1<<<1024, 256, 0, stream>>>(condout, noise, pc, m_w1, ws0, ws0 + 4194304);
    k_mconv2<<<512, 256, 0, stream>>>(ws0, ws0 + 4194304, m_w2, m_b2, y2, statB);
    k_bnfinal<<<1, 64, 0, stream>>>(statB, m_bng, m_bnb, 8, 512, ssB);
    k_bnapply<<<1024, 256, 0, stream>>>(y2, ssB, 8, y2, 1, 262144);
    k_lin<<<1024, 256, 0, stream>>>(y2, lin_w, ws0);
    k_linred<<<1024, 256, 0, stream>>>(ws0, lin_b, flatB);
    k_heads<<<dim3(8,6,16), 256, 0, stream>>>(flatB, circ_w, slid_w, partH);
    k_assemble<<<256, 256, 0, stream>>>(partH, circ_b, slid_b, gumbel, genout);
}

// Round 14
// 662.596 us; speedup vs baseline: 1.0377x; 1.0377x over previous
//
#include <hip/hip_runtime.h>
#include <math.h>

#define NB 256
#define LL 512
#define CIN 514

__device__ __forceinline__ float lrelu(float x) { return x >= 0.f ? x : 0.2f * x; }

// ---------------- positional encoding table [128][512], fp64 math like numpy ----------------
__global__ __launch_bounds__(256) void k_pos(float* __restrict__ pos) {
    int idx = blockIdx.x * 256 + threadIdx.x;   // 65536 total
    int c = idx >> 9, l = idx & 511;
    double e = (double)(2 * (c >> 1)) / 128.0;
    double dv = 1.0 / pow(10000.0, e);
    double a = (double)l * dv;
    pos[idx] = (float)((c & 1) ? cos(a) : sin(a));
}

// ---------------- posconv: PC[o][l] = bias[o] + sum_c sum_k W[o][c][k]*POS[c][l+k-3] ----------------
__global__ __launch_bounds__(256) void k_posconv(const float* __restrict__ POS, const float* __restrict__ W,
                                                 const float* __restrict__ bias, float* __restrict__ PC) {
    const int t = threadIdx.x;
    const int o = blockIdx.x >> 4, l0 = (blockIdx.x & 15) * 32;
    const int l = l0 + (t & 31), cs = t >> 5;
    float acc = 0.f;
    for (int ci = 0; ci < 16; ++ci) {
        int c = cs * 16 + ci;
        float wv[7];
#pragma unroll
        for (int k = 0; k < 7; ++k) wv[k] = W[o * 896 + c * 7 + k];
#pragma unroll
        for (int k = 0; k < 7; ++k) {
            int gl = l + k - 3;
            if (gl >= 0 && gl < LL) acc += wv[k] * POS[c * LL + gl];
        }
    }
    __shared__ float red[8][33];
    red[cs][t & 31] = acc;
    __syncthreads();
    if (cs == 0) {
        float s = bias[o];
#pragma unroll
        for (int j = 0; j < 8; ++j) s += red[j][t & 31];
        PC[o * LL + l0 + (t & 31)] = s;
    }
}

// ---------------- conv1 v6: 1x1, 514->32. Split n x l-chunk(256) x K-quarter. Low-VGPR (acc 8x4). ----------------
// grid 2048: n = b>>3, lh = (b>>2)&1, z = b&3.
__global__ __launch_bounds__(256, 4) void k_conv1(const float* __restrict__ X, const float* __restrict__ W,
                                                  float* __restrict__ Pbase) {
    __shared__ __align__(16) float As[16][260];   // [kk][l]
    __shared__ __align__(16) float Bs[16][36];    // [kk][o]
    const int t = threadIdx.x;
    const int n = blockIdx.x >> 3, lh = (blockIdx.x >> 2) & 1, z = blockIdx.x & 3;
    const int l0 = lh * 256;
    const int kbase = z * 128;
    const int nch = (z == 3) ? 9 : 8;
    const int tl = t & 63, to = t >> 6;
    const size_t rowbase = (size_t)n * 512 * CIN;

    float acc[8][4];   // [oi][p]: o = to*8+oi, l = l0 + tl*4 + p
#pragma unroll
    for (int oi = 0; oi < 8; ++oi)
#pragma unroll
        for (int p = 0; p < 4; ++p) acc[oi][p] = 0.f;

    for (int c = 0; c < nch; ++c) {
        const int kb = kbase + c * 16;
        if (c) __syncthreads();
#pragma unroll
        for (int ps = 0; ps < 8; ++ps) {
            int idx = ps * 256 + t;
            int pos = idx >> 3, kp = idx & 7;
            int gk = kb + kp * 2;
            float2 v = {0.f, 0.f};
            if (gk + 1 < CIN) v = *(const float2*)(X + rowbase + (size_t)(l0 + pos) * CIN + gk);
            else if (gk < CIN) v.x = X[rowbase + (size_t)(l0 + pos) * CIN + gk];
            As[kp * 2][pos] = v.x;
            As[kp * 2 + 1][pos] = v.y;
        }
        {
            int o = t >> 3, kp = t & 7;
            int gk = kb + kp * 2;
            float2 v = {0.f, 0.f};
            if (gk + 1 < CIN) v = *(const float2*)(W + (size_t)o * CIN + gk);
            else if (gk < CIN) v.x = W[(size_t)o * CIN + gk];
            Bs[kp * 2][o] = v.x;
            Bs[kp * 2 + 1][o] = v.y;
        }
        __syncthreads();
#pragma unroll
        for (int kk = 0; kk < 16; ++kk) {
            float4 a  = *(const float4*)&As[kk][tl * 4];
            float4 b0 = *(const float4*)&Bs[kk][to * 8];
            float4 b1 = *(const float4*)&Bs[kk][to * 8 + 4];
            float av[4] = {a.x, a.y, a.z, a.w};
            float bv[8] = {b0.x, b0.y, b0.z, b0.w, b1.x, b1.y, b1.z, b1.w};
#pragma unroll
            for (int oi = 0; oi < 8; ++oi)
#pragma unroll
                for (int p = 0; p < 4; ++p) acc[oi][p] += av[p] * bv[oi];
        }
    }

    float* P = Pbase + (size_t)z * 4194304;
#pragma unroll
    for (int oi = 0; oi < 8; ++oi) {
        int o = to * 8 + oi;
        float4 v = {acc[oi][0], acc[oi][1], acc[oi][2], acc[oi][3]};
        *(float4*)(P + ((size_t)n * 32 + o) * LL + l0 + tl * 4) = v;
    }
}

// ---------------- conv2: k=3 pad=1, 32->16, + bias. Input = lrelu(P0..P3+b1) fused; emits BN partials ----------------
__global__ __launch_bounds__(256) void k_conv2(const float* __restrict__ Pbase,
                                               const float* __restrict__ b1, const float* __restrict__ W,
                                               const float* __restrict__ bias, float* __restrict__ out,
                                               float* __restrict__ part) {
    __shared__ __align__(16) float Xs[32][264];
    __shared__ __align__(16) float Ws[16][32][4];
    __shared__ float reds[16][33], redq[16][33];
    const int t = threadIdx.x;
    const int bid = blockIdx.x;
    const int n = bid >> 1, l0 = (bid & 1) * 256;
    for (int idx = t; idx < 32 * 258; idx += 256) {
        int i = idx / 258, j = idx % 258;
        int gl = l0 - 1 + j;
        float v = 0.f;
        if (gl >= 0 && gl < LL) {
            size_t off = ((size_t)n * 32 + i) * LL + gl;
            v = lrelu(Pbase[off] + Pbase[off + 4194304] + Pbase[off + 8388608] + Pbase[off + 12582912] + b1[i]);
        }
        Xs[i][j] = v;
    }
    for (int idx = t; idx < 1536; idx += 256) {
        int o = idx / 96, r = idx % 96;
        Ws[o][r / 3][r % 3] = W[idx];
    }
    __syncthreads();
    const int tx = t & 31, ty = t >> 5;
    float acc[2][8];
#pragma unroll
    for (int q = 0; q < 2; ++q)
#pragma unroll
        for (int p = 0; p < 8; ++p) acc[q][p] = 0.f;
    for (int i = 0; i < 32; ++i) {
        float4 a0 = *(const float4*)&Xs[i][tx*8];
        float4 a1 = *(const float4*)&Xs[i][tx*8+4];
        float4 a2 = *(const float4*)&Xs[i][tx*8+8];
        float a[12] = {a0.x,a0.y,a0.z,a0.w,a1.x,a1.y,a1.z,a1.w,a2.x,a2.y,a2.z,a2.w};
#pragma unroll
        for (int q = 0; q < 2; ++q) {
            float4 b = *(const float4*)&Ws[ty*2+q][i][0];
#pragma unroll
            for (int p = 0; p < 8; ++p)
                acc[q][p] += a[p]*b.x + a[p+1]*b.y + a[p+2]*b.z;
        }
    }
#pragma unroll
    for (int q = 0; q < 2; ++q) {
        int o = ty*2+q; float bb = bias[o];
        float s = 0.f, sq = 0.f;
#pragma unroll
        for (int h = 0; h < 2; ++h) {
            float4 v;
            v.x = acc[q][h*4+0] + bb; v.y = acc[q][h*4+1] + bb;
            v.z = acc[q][h*4+2] + bb; v.w = acc[q][h*4+3] + bb;
            s += v.x + v.y + v.z + v.w;
            sq += v.x*v.x + v.y*v.y + v.z*v.z + v.w*v.w;
            *(float4*)(out + ((size_t)n*16 + o)*LL + l0 + tx*8 + h*4) = v;
        }
        reds[o][tx] = s;
        redq[o][tx] = sq;
    }
    __syncthreads();
    if (t < 16) {
        float s = 0.f, sq = 0.f;
#pragma unroll
        for (int x = 0; x < 32; ++x) { s += reds[t][x]; sq += redq[t][x]; }
        part[((size_t)t * 512 + bid) * 2] = s;
        part[((size_t)t * 512 + bid) * 2 + 1] = sq;
    }
}

// ---------------- BN final: reduce S slices per channel ----------------
__global__ void k_bnfinal(const float* __restrict__ part, const float* __restrict__ g,
                          const float* __restrict__ b, int C, int S, float* __restrict__ ss) {
    int ch = threadIdx.x;
    if (ch >= C) return;
    float s = 0.f, q = 0.f;
    for (int j = 0; j < S; ++j) { s += part[((size_t)ch*S + j)*2]; q += part[((size_t)ch*S + j)*2 + 1]; }
    float mean = s * (1.f/131072.f);
    float var = q * (1.f/131072.f) - mean*mean;
    float sc = g[ch] / sqrtf(var + 1e-5f);
    ss[ch] = sc;
    ss[C + ch] = b[ch] - mean * sc;
}

__global__ __launch_bounds__(256) void k_bnapply(const float* __restrict__ src, const float* __restrict__ ss,
        int C, float* __restrict__ dst, int act, int total4) {
    int i4 = blockIdx.x * 256 + threadIdx.x;
    if (i4 >= total4) return;
    int i = i4 << 2;
    int ch = (i >> 9) % C;
    float sc = ss[ch], sh = ss[C + ch];
    float4 v = reinterpret_cast<const float4*>(src)[i4];
    v.x = v.x*sc + sh; v.y = v.y*sc + sh; v.z = v.z*sc + sh; v.w = v.w*sc + sh;
    if (act) { v.x = lrelu(v.x); v.y = lrelu(v.y); v.z = lrelu(v.z); v.w = lrelu(v.w); }
    reinterpret_cast<float4*>(dst)[i4] = v;
}

// ---------------- m_conv1 v6: k=7 pad=3, 128->32. K-split x2, 8 half-stages, LDS dbuf, coalesced NZ staging ----------------
__global__ __launch_bounds__(256) void k_mconv1(const float* __restrict__ C16, const float* __restrict__ NZ,
        const float* __restrict__ PC, const float* __restrict__ W,
        float* __restrict__ out0, float* __restrict__ out1) {
    __shared__ __align__(16) float Gs[2][8][268];
    __shared__ __align__(16) float Ws[2][32][8][8];
    const int t = threadIdx.x;
    const int n = blockIdx.x >> 2, l0 = ((blockIdx.x >> 1) & 1) * 256, z = blockIdx.x & 1;
    const int tx = t & 31, ty = t >> 5;
    float acc[4][8];
#pragma unroll
    for (int q = 0; q < 4; ++q)
#pragma unroll
        for (int p = 0; p < 8; ++p) acc[q][p] = 0.f;

    float4 ga0, ga1, gb0, gb1;
    float wpf[8];
    const int gl1 = l0 - 3 + t;
    const bool ok1 = (gl1 >= 0 && gl1 < LL);
    const int gl2 = l0 + 253 + t;
    const bool ok2 = (t < 6) && (gl2 < LL);

    auto LOADG = [&](int hh) {
        const float4 f4z = {0.f, 0.f, 0.f, 0.f};
        ga0 = f4z; ga1 = f4z; gb0 = f4z; gb1 = f4z;
        if (z == 0 && hh < 2) {
            const float* base = C16 + ((size_t)n * 16 + hh * 8) * LL;
            if (ok1) {
                const float* p = base + gl1;
                ga0.x = p[0];      ga0.y = p[LL];     ga0.z = p[2*LL];  ga0.w = p[3*LL];
                ga1.x = p[4*LL];   ga1.y = p[5*LL];   ga1.z = p[6*LL];  ga1.w = p[7*LL];
            }
            if (ok2) {
                const float* p = base + gl2;
                gb0.x = p[0];      gb0.y = p[LL];     gb0.z = p[2*LL];  gb0.w = p[3*LL];
                gb1.x = p[4*LL];   gb1.y = p[5*LL];   gb1.z = p[6*LL];  gb1.w = p[7*LL];
            }
        } else {
            const int nzc = z * 64 + hh * 8 - 16;
            if (ok1) {
                const float* p = NZ + ((size_t)n * LL + gl1) * 112 + nzc;
                ga0 = *(const float4*)p;
                ga1 = *(const float4*)(p + 4);
            }
            if (ok2) {
                const float* p = NZ + ((size_t)n * LL + gl2) * 112 + nzc;
                gb0 = *(const float4*)p;
                gb1 = *(const float4*)(p + 4);
            }
        }
    };
    auto WRITEG = [&](int bb) {
        Gs[bb][0][t] = ga0.x; Gs[bb][1][t] = ga0.y; Gs[bb][2][t] = ga0.z; Gs[bb][3][t] = ga0.w;
        Gs[bb][4][t] = ga1.x; Gs[bb][5][t] = ga1.y; Gs[bb][6][t] = ga1.z; Gs[bb][7][t] = ga1.w;
        if (t < 6) {
            Gs[bb][0][256+t] = gb0.x; Gs[bb][1][256+t] = gb0.y; Gs[bb][2][256+t] = gb0.z; Gs[bb][3][256+t] = gb0.w;
            Gs[bb][4][256+t] = gb1.x; Gs[bb][5][256+t] = gb1.y; Gs[bb][6][256+t] = gb1.z; Gs[bb][7][256+t] = gb1.w;
        }
    };
    auto LOADW = [&](int hh) {
        const int b7 = (z * 64 + hh * 8) * 7;
#pragma unroll
        for (int p = 0; p < 8; ++p) {
            int idx = p * 256 + t;
            int k = idx & 7, ci = (idx >> 3) & 7, o = idx >> 6;
            wpf[p] = (k < 7) ? W[(size_t)o * 896 + b7 + ci * 7 + k] : 0.f;
        }
    };
    auto WRITEW = [&](int bb) {
#pragma unroll
        for (int p = 0; p < 8; ++p) {
            int idx = p * 256 + t;
            int k = idx & 7;
            if (k < 7) {
                int ci = (idx >> 3) & 7, o = idx >> 6;
                Ws[bb][o][ci][k] = wpf[p];
            }
        }
    };

    LOADG(0);
    LOADW(0);
    WRITEG(0);
    WRITEW(0);
    __syncthreads();

    for (int h = 0; h < 8; ++h) {
        const int hb = h & 1;
        if (h < 7) {
            LOADG(h + 1);
            LOADW(h + 1);
        }
        for (int ci = 0; ci < 8; ++ci) {
            float4 a0 = *(const float4*)&Gs[hb][ci][tx*4];
            float4 a1 = *(const float4*)&Gs[hb][ci][tx*4+4];
            float4 a2 = *(const float4*)&Gs[hb][ci][tx*4+8];
            float4 a3 = *(const float4*)&Gs[hb][ci][128+tx*4];
            float4 a4 = *(const float4*)&Gs[hb][ci][128+tx*4+4];
            float4 a5 = *(const float4*)&Gs[hb][ci][128+tx*4+8];
            float aA[12] = {a0.x,a0.y,a0.z,a0.w,a1.x,a1.y,a1.z,a1.w,a2.x,a2.y,a2.z,a2.w};
            float aB[12] = {a3.x,a3.y,a3.z,a3.w,a4.x,a4.y,a4.z,a4.w,a5.x,a5.y,a5.z,a5.w};
#pragma unroll
            for (int q = 0; q < 4; ++q) {
                float4 b0 = *(const float4*)&Ws[hb][ty*4+q][ci][0];
                float4 b1 = *(const float4*)&Ws[hb][ty*4+q][ci][4];
                float b[7] = {b0.x,b0.y,b0.z,b0.w,b1.x,b1.y,b1.z};
#pragma unroll
                for (int p = 0; p < 4; ++p) {
#pragma unroll
                    for (int k = 0; k < 7; ++k) {
                        acc[q][p]   += aA[p+k]*b[k];
                        acc[q][4+p] += aB[p+k]*b[k];
                    }
                }
            }
        }
        if (h < 7) {
            const int nb = hb ^ 1;
            WRITEG(nb);
            WRITEW(nb);
            __syncthreads();
        }
    }

    float* out = z ? out1 : out0;
#pragma unroll
    for (int q = 0; q < 4; ++q) {
        int o = ty*4 + q;
        float4 p0 = {0.f,0.f,0.f,0.f}, p1 = {0.f,0.f,0.f,0.f};
        if (z == 0) {
            p0 = *(const float4*)(PC + o*LL + l0 + tx*4);
            p1 = *(const float4*)(PC + o*LL + l0 + 128 + tx*4);
        }
        float4 v0 = {acc[q][0]+p0.x, acc[q][1]+p0.y, acc[q][2]+p0.z, acc[q][3]+p0.w};
        float4 v1 = {acc[q][4]+p1.x, acc[q][5]+p1.y, acc[q][6]+p1.z, acc[q][7]+p1.w};
        *(float4*)(out + ((size_t)n*32 + o)*LL + l0 + tx*4) = v0;
        *(float4*)(out + ((size_t)n*32 + o)*LL + l0 + 128 + tx*4) = v1;
    }
}

// ---------------- m_conv2: k=3 pad=1, 32->8, + bias. Input = lrelu(P0+P1) fused; emits BN partials ----------------
__global__ __launch_bounds__(256) void k_mconv2(const float* __restrict__ P0, const float* __restrict__ P1,
        const float* __restrict__ W, const float* __restrict__ bias, float* __restrict__ out,
        float* __restrict__ part) {
    __shared__ __align__(16) float Xs[32][264];
    __shared__ __align__(16) float Ws[8][32][4];
    __shared__ float reds[8][33], redq[8][33];
    const int t = threadIdx.x;
    const int bid = blockIdx.x;
    const int n = bid >> 1, l0 = (bid & 1) * 256;
    for (int idx = t; idx < 32 * 258; idx += 256) {
        int i = idx / 258, j = idx % 258;
        int gl = l0 - 1 + j;
        float v = 0.f;
        if (gl >= 0 && gl < LL) {
            size_t off = ((size_t)n * 32 + i) * LL + gl;
            v = lrelu(P0[off] + P1[off]);
        }
        Xs[i][j] = v;
    }
    for (int idx = t; idx < 768; idx += 256) {
        int o = idx / 96, r = idx % 96;
        Ws[o][r / 3][r % 3] = W[idx];
    }
    __syncthreads();
    const int tx = t & 31, ty = t >> 5;
    float acc[8];
#pragma unroll
    for (int p = 0; p < 8; ++p) acc[p] = 0.f;
    for (int i = 0; i < 32; ++i) {
        float4 a0 = *(const float4*)&Xs[i][tx*8];
        float4 a1 = *(const float4*)&Xs[i][tx*8+4];
        float4 a2 = *(const float4*)&Xs[i][tx*8+8];
        float a[12] = {a0.x,a0.y,a0.z,a0.w,a1.x,a1.y,a1.z,a1.w,a2.x,a2.y,a2.z,a2.w};
        float4 b = *(const float4*)&Ws[ty][i][0];
#pragma unroll
        for (int p = 0; p < 8; ++p)
            acc[p] += a[p]*b.x + a[p+1]*b.y + a[p+2]*b.z;
    }
    float bb = bias[ty];
    float s = 0.f, sq = 0.f;
#pragma unroll
    for (int h = 0; h < 2; ++h) {
        float4 v;
        v.x = acc[h*4+0] + bb; v.y = acc[h*4+1] + bb;
        v.z = acc[h*4+2] + bb; v.w = acc[h*4+3] + bb;
        s += v.x + v.y + v.z + v.w;
        sq += v.x*v.x + v.y*v.y + v.z*v.z + v.w*v.w;
        *(float4*)(out + ((size_t)n*8 + ty)*LL + l0 + tx*8 + h*4) = v;
    }
    reds[ty][tx] = s;
    redq[ty][tx] = sq;
    __syncthreads();
    if (t < 8) {
        float ss = 0.f, qq = 0.f;
#pragma unroll
        for (int x = 0; x < 32; ++x) { ss += reds[t][x]; qq += redq[t][x]; }
        part[((size_t)t * 512 + bid) * 2] = ss;
        part[((size_t)t * 512 + bid) * 2 + 1] = qq;
    }
}

// ---------------- linear 4096x4096 v4: 128x128 tile, BK=16, 8x8 micro, z=16, no prefetch ----------------
__global__ __launch_bounds__(256) void k_lin(const float* __restrict__ A, const float* __restrict__ B,
                                             float* __restrict__ part) {
    __shared__ __align__(16) float As[16][132];
    __shared__ __align__(16) float Bs[16][132];
    const int t = threadIdx.x;
    const int bid = blockIdx.x;
    const int xcd = bid & 7, j = bid >> 3;
    const int z = j >> 3;
    const int m0 = ((j >> 2) & 1) * 128;
    const int f0 = (xcd * 4 + (j & 3)) * 128;
    const int k0base = z * 256;
    const int sar = t & 127, saq = t >> 7;
    const int sbr = t >> 4, sbq = t & 15;
    const int mq = (t & 15) * 4, fq = (t >> 4) * 4;

    float acc[8][8];
#pragma unroll
    for (int i = 0; i < 8; ++i)
#pragma unroll
        for (int q = 0; q < 8; ++q) acc[i][q] = 0.f;

    for (int it = 0; it < 16; ++it) {
        const int k0 = k0base + it * 16;
        {
            const float* pA = A + (size_t)(m0 + sar) * 4096 + k0 + saq * 8;
            float4 a0 = *(const float4*)(pA);
            float4 a1 = *(const float4*)(pA + 4);
            const float* pB = B + (size_t)(k0 + sbr) * 4096 + f0 + sbq * 8;
            float4 b0 = *(const float4*)(pB);
            float4 b1 = *(const float4*)(pB + 4);
            As[saq*8+0][sar] = a0.x; As[saq*8+1][sar] = a0.y; As[saq*8+2][sar] = a0.z; As[saq*8+3][sar] = a0.w;
            As[saq*8+4][sar] = a1.x; As[saq*8+5][sar] = a1.y; As[saq*8+6][sar] = a1.z; As[saq*8+7][sar] = a1.w;
            *(float4*)&Bs[sbr][sbq*8] = b0;
            *(float4*)&Bs[sbr][sbq*8+4] = b1;
        }
        __syncthreads();
#pragma unroll
        for (int kk = 0; kk < 16; ++kk) {
            float4 a0 = *(const float4*)&As[kk][mq];
            float4 a1 = *(const float4*)&As[kk][mq + 64];
            float4 b0 = *(const float4*)&Bs[kk][fq];
            float4 b1 = *(const float4*)&Bs[kk][fq + 64];
            float av[8] = {a0.x,a0.y,a0.z,a0.w,a1.x,a1.y,a1.z,a1.w};
            float bv[8] = {b0.x,b0.y,b0.z,b0.w,b1.x,b1.y,b1.z,b1.w};
#pragma unroll
            for (int i = 0; i < 8; ++i)
#pragma unroll
                for (int q = 0; q < 8; ++q) acc[i][q] += av[i] * bv[q];
        }
        __syncthreads();
    }

#pragma unroll
    for (int i = 0; i < 8; ++i) {
        int m = m0 + mq + (i & 3) + (i >> 2) * 64;
        float4 v0 = {acc[i][0], acc[i][1], acc[i][2], acc[i][3]};
        float4 v1 = {acc[i][4], acc[i][5], acc[i][6], acc[i][7]};
        *(float4*)(part + ((size_t)z * 256 + m) * 4096 + f0 + fq) = v0;
        *(float4*)(part + ((size_t)z * 256 + m) * 4096 + f0 + fq + 64) = v1;
    }
}

// sum 16 K-partials + bias + lrelu
__global__ __launch_bounds__(256) void k_linred(const float* __restrict__ part, const float* __restrict__ bias,
        float* __restrict__ out) {
    int i4 = blockIdx.x*256 + threadIdx.x;   // < 262144
    int i = i4 << 2;
    int f = i & 4095;
    float4 s = *(const float4*)(bias + f);
#pragma unroll
    for (int zz = 0; zz < 16; ++zz) {
        float4 p = ((const float4*)(part + (size_t)zz * 1048576))[i4];
        s.x += p.x; s.y += p.y; s.z += p.z; s.w += p.w;
    }
    float4 r;
    r.x = lrelu(s.x); r.y = lrelu(s.y); r.z = lrelu(s.z); r.w = lrelu(s.w);
    ((float4*)out)[i4] = r;
}

// ---------------- heads: [4096x512 | 4096x256], split-K (16), no prefetch ----------------
__global__ __launch_bounds__(256) void k_heads(const float* __restrict__ A, const float* __restrict__ CW,
        const float* __restrict__ SW, float* __restrict__ part) {
    __shared__ __align__(16) float As[32][36];
    __shared__ __align__(16) float Bs[32][132];
    const int t = threadIdx.x;
    const int m0 = blockIdx.x * 32, f0 = blockIdx.y * 128, z = blockIdx.z;
    const float* B; int ldb, fb;
    if (f0 < 512) { B = CW; ldb = 512; fb = f0; } else { B = SW; ldb = 256; fb = f0 - 512; }
    const int tm = t & 7, tf = t >> 3;
    const int mi = t >> 3, kq = t & 7;
    float acc[4][4];
#pragma unroll
    for (int pm = 0; pm < 4; ++pm)
#pragma unroll
        for (int pf = 0; pf < 4; ++pf) acc[pm][pf] = 0.f;
    for (int k0 = z * 256; k0 < z * 256 + 256; k0 += 32) {
        float4 av = *(const float4*)(A + (size_t)(m0 + mi) * 4096 + k0 + kq * 4);
        As[kq*4+0][mi] = av.x; As[kq*4+1][mi] = av.y; As[kq*4+2][mi] = av.z; As[kq*4+3][mi] = av.w;
#pragma unroll
        for (int pass = 0; pass < 4; ++pass) {
            int fi = pass * 32 + kq * 4;
            *(float4*)&Bs[mi][fi] = *(const float4*)(B + (size_t)(k0 + mi) * ldb + fb + fi);
        }
        __syncthreads();
#pragma unroll 8
        for (int kk = 0; kk < 32; ++kk) {
            float4 a = *(const float4*)&As[kk][tm * 4];
            float4 b = *(const float4*)&Bs[kk][tf * 4];
            float avv[4] = {a.x,a.y,a.z,a.w};
            float bvv[4] = {b.x,b.y,b.z,b.w};
#pragma unroll
            for (int pm = 0; pm < 4; ++pm)
#pragma unroll
                for (int pf = 0; pf < 4; ++pf) acc[pm][pf] += avv[pm]*bvv[pf];
        }
        __syncthreads();
    }
#pragma unroll
    for (int pm = 0; pm < 4; ++pm) {
        float4 v = {acc[pm][0], acc[pm][1], acc[pm][2], acc[pm][3]};
        *(float4*)(part + ((size_t)z * 256 + m0 + tm * 4 + pm) * 768 + f0 + tf * 4) = v;
    }
}

// ---------------- assemble (fused headred) + gumbel softmax(hard) ----------------
__global__ __launch_bounds__(256) void k_assemble(const float* __restrict__ part, const float* __restrict__ cb,
        const float* __restrict__ sb, const float* __restrict__ gum, float* __restrict__ out) {
    __shared__ float buf[768];
    const int n = blockIdx.x;
    const int t = threadIdx.x;
#pragma unroll
    for (int rep = 0; rep < 3; ++rep) {
        int f = rep * 256 + t;
        float s = 0.f;
#pragma unroll
        for (int ks = 0; ks < 16; ++ks) s += part[((size_t)(ks * 256 + n)) * 768 + f];
        s += (f < 512) ? cb[f] : sb[f - 512];
        buf[f] = s;
    }
    __syncthreads();
    if (t >= 128) return;
    const int b = t;
    const float* cp = buf;
    const float* sp = buf + 512;
    float sl0 = sp[2*b], sl1 = sp[2*b+1];
    int s = sl1 > sl0 ? 1 : 0;
    int prevb = 0;
    if (b > 0) prevb = (sp[2*b-1] > sp[2*b-2]) ? 1 : 0;
    bool body = (s == 1) && (b < 127);
    bool tail = ((s == 1) && (b == 127)) || ((s == 0) && (prevb == 1));
    float c0a = cp[4*b], c0b = cp[4*b+1], c1a = cp[4*b+2], c1b = cp[4*b+3];
    bool cA = c0b > c0a, cB = c1b > c1a;
    float rows[4][3];
    if (body || tail)      { rows[0][0]=sl0; rows[0][1]=0.f; rows[0][2]=sl1; }
    else if (cA)           { rows[0][0]=c0a; rows[0][1]=c0b; rows[0][2]=0.f; }
    else                   { rows[0][0]=1.f; rows[0][1]=0.f; rows[0][2]=0.f; }
    if (body)              { rows[1][0]=0.f; rows[1][1]=0.f; rows[1][2]=1.f; }
    else                   { rows[1][0]=1.f; rows[1][1]=0.f; rows[1][2]=0.f; }
    if (body)              { rows[2][0]=0.f; rows[2][1]=0.f; rows[2][2]=1.f; }
    else if (cB)           { rows[2][0]=c1a; rows[2][1]=c1b; rows[2][2]=0.f; }
    else                   { rows[2][0]=1.f; rows[2][1]=0.f; rows[2][2]=0.f; }
    rows[3][0]=rows[1][0]; rows[3][1]=rows[1][1]; rows[3][2]=rows[1][2];
#pragma unroll
    for (int r = 0; r < 4; ++r) {
        int l = 4*b + r;
        const float* u = gum + ((size_t)n*512 + l)*3;
        float g0 = -logf(-logf(u[0]+1e-10f)+1e-10f);
        float g1 = -logf(-logf(u[1]+1e-10f)+1e-10f);
        float g2 = -logf(-logf(u[2]+1e-10f)+1e-10f);
        float t0 = rows[r][0]+g0, t1 = rows[r][1]+g1, t2 = rows[r][2]+g2;
        int am = 0; float mv = t0;
        if (t1 > mv) { am = 1; mv = t1; }
        if (t2 > mv) { am = 2; mv = t2; }
        float e0 = expf(t0-mv), e1 = expf(t1-mv), e2 = expf(t2-mv);
        float ssum = e0+e1+e2;
        float y0 = e0/ssum, y1 = e1/ssum, y2 = e2/ssum;
        float* o = out + ((size_t)n*512 + l)*3;
        o[0] = ((am==0?1.f:0.f) + y0) - y0;
        o[1] = ((am==1?1.f:0.f) + y1) - y1;
        o[2] = ((am==2?1.f:0.f) + y2) - y2;
    }
}

extern "C" void kernel_launch(void* const* d_in, const int* in_sizes, int n_in,
                              void* d_out, int out_size, void* d_ws, size_t ws_size,
                              hipStream_t stream) {
    const float* noise   = (const float*)d_in[0];
    const float* cond    = (const float*)d_in[1];
    const float* gumbel  = (const float*)d_in[2];
    const float* ext_w1  = (const float*)d_in[3];
    const float* ext_b1  = (const float*)d_in[4];
    const float* ext_w2  = (const float*)d_in[5];
    const float* ext_b2  = (const float*)d_in[6];
    const float* ext_bng = (const float*)d_in[7];
    const float* ext_bnb = (const float*)d_in[8];
    const float* m_w1    = (const float*)d_in[9];
    const float* m_b1    = (const float*)d_in[10];
    const float* m_w2    = (const float*)d_in[11];
    const float* m_b2    = (const float*)d_in[12];
    const float* m_bng   = (const float*)d_in[13];
    const float* m_bnb   = (const float*)d_in[14];
    const float* lin_w   = (const float*)d_in[15];
    const float* lin_b   = (const float*)d_in[16];
    const float* circ_w  = (const float*)d_in[17];
    const float* circ_b  = (const float*)d_in[18];
    const float* slid_w  = (const float*)d_in[19];
    const float* slid_b  = (const float*)d_in[20];

    float* genout  = (float*)d_out;                       // [256][512][3]
    float* condout = (float*)d_out + 256*512*3;           // [256][16][512]

    float* w     = (float*)d_ws;
    float* ws0   = w;                  // 16,777,216 floats: conv1 partials z0-3 / mconv1 partials / k_lin partials
    float* y2    = ws0 + 16777216;     // 2097152 (h2 raw / flat_in)
    float* posb  = y2 + 2097152;       // 65536
    float* pc    = posb + 65536;       // 16384  (posconv table [32][512])
    float* flatB = pc + 16384;         // 1048576
    float* partH = flatB + 1048576;    // 3145728 (heads partials z=16)
    float* statA = partH + 3145728;    // 16384 (conv2 BN partials: 16ch x 512 x 2)
    float* ssA   = statA + 16384;      // 64
    float* statB = ssA + 64;           // 8192 (mconv2 BN partials: 8ch x 512 x 2)
    float* ssB   = statB + 8192;       // 64

    k_pos<<<256, 256, 0, stream>>>(posb);
    k_posconv<<<512, 256, 0, stream>>>(posb, m_w1, m_b1, pc);
    k_conv1<<<2048, 256, 0, stream>>>(cond, ext_w1, ws0);
    k_conv2<<<512, 256, 0, stream>>>(ws0, ext_b1, ext_w2, ext_b2, y2, statA);
    k_bnfinal<<<1, 64, 0, stream>>>(statA, ext_bng, ext_bnb, 16, 512, ssA);
    k_bnapply<<<2048, 256, 0, stream>>>(y2, ssA, 16, condout, 0, 524288);
    k_mconv1<<<1024, 256, 0, stream>>>(condout, noise, pc, m_w1, ws0, ws0 + 4194304);
    k_mconv2<<<512, 256, 0, stream>>>(ws0, ws0 + 4194304, m_w2, m_b2, y2, statB);
    k_bnfinal<<<1, 64, 0, stream>>>(statB, m_bng, m_bnb, 8, 512, ssB);
    k_bnapply<<<1024, 256, 0, stream>>>(y2, ssB, 8, y2, 1, 262144);
    k_lin<<<1024, 256, 0, stream>>>(y2, lin_w, ws0);
    k_linred<<<1024, 256, 0, stream>>>(ws0, lin_b, flatB);
    k_heads<<<dim3(8,6,16), 256, 0, stream>>>(flatB, circ_w, slid_w, partH);
    k_assemble<<<256, 256, 0, stream>>>(partH, circ_b, slid_b, gumbel, genout);
}

// Round 15
// 584.661 us; speedup vs baseline: 1.1761x; 1.1333x over previous
//
#include <hip/hip_runtime.h>
#include <math.h>

#define NB 256
#define LL 512
#define CIN 514

__device__ __forceinline__ float lrelu(float x) { return x >= 0.f ? x : 0.2f * x; }

// ---------------- positional encoding table [128][512], fp64 math like numpy ----------------
__global__ __launch_bounds__(256) void k_pos(float* __restrict__ pos) {
    int idx = blockIdx.x * 256 + threadIdx.x;   // 65536 total
    int c = idx >> 9, l = idx & 511;
    double e = (double)(2 * (c >> 1)) / 128.0;
    double dv = 1.0 / pow(10000.0, e);
    double a = (double)l * dv;
    pos[idx] = (float)((c & 1) ? cos(a) : sin(a));
}

// ---------------- posconv: PC[o][l] = bias[o] + sum_c sum_k W[o][c][k]*POS[c][l+k-3] ----------------
__global__ __launch_bounds__(256) void k_posconv(const float* __restrict__ POS, const float* __restrict__ W,
                                                 const float* __restrict__ bias, float* __restrict__ PC) {
    const int t = threadIdx.x;
    const int o = blockIdx.x >> 4, l0 = (blockIdx.x & 15) * 32;
    const int l = l0 + (t & 31), cs = t >> 5;
    float acc = 0.f;
    for (int ci = 0; ci < 16; ++ci) {
        int c = cs * 16 + ci;
        float wv[7];
#pragma unroll
        for (int k = 0; k < 7; ++k) wv[k] = W[o * 896 + c * 7 + k];
#pragma unroll
        for (int k = 0; k < 7; ++k) {
            int gl = l + k - 3;
            if (gl >= 0 && gl < LL) acc += wv[k] * POS[c * LL + gl];
        }
    }
    __shared__ float red[8][33];
    red[cs][t & 31] = acc;
    __syncthreads();
    if (cs == 0) {
        float s = bias[o];
#pragma unroll
        for (int j = 0; j < 8; ++j) s += red[j][t & 31];
        PC[o * LL + l0 + (t & 31)] = s;
    }
}

// ---------------- conv1 v7: 1x1, 514->32. Full-K per block, 128-row l-chunks, no partials ----------------
// grid 1024: n = b>>2, l0 = (b&3)*128. K in 17 LDS chunks of 32 (128B/row/wave reads).
__global__ __launch_bounds__(256, 4) void k_conv1(const float* __restrict__ X, const float* __restrict__ W,
                                                  float* __restrict__ P) {
    __shared__ __align__(16) float As[32][132];   // [kk][l], 128 + pad
    __shared__ __align__(16) float Bs[32][36];    // [kk][o]
    const int t = threadIdx.x;
    const int n = blockIdx.x >> 2, l0 = (blockIdx.x & 3) * 128;
    const int tl = t & 31, to = t >> 5;           // tl: 32 l-slots of 4; to: 8 o-groups of 4
    const size_t rowbase = (size_t)n * 512 * CIN;

    float acc[4][4];   // [oi][p]: o = to*4+oi, l = l0 + tl*4 + p
#pragma unroll
    for (int oi = 0; oi < 4; ++oi)
#pragma unroll
        for (int p = 0; p < 4; ++p) acc[oi][p] = 0.f;

    for (int c = 0; c < 17; ++c) {
        const int kb = c * 32;
        if (c) __syncthreads();
        // stage A: 128 rows x 32 k; wave reads 128B contiguous per row
#pragma unroll
        for (int ps = 0; ps < 4; ++ps) {
            int idx = ps * 256 + t;
            int pos = idx >> 3, kq = idx & 7;
            int gk = kb + kq * 4;
            const float* src = X + rowbase + (size_t)(l0 + pos) * CIN;
            float4 v = {0.f, 0.f, 0.f, 0.f};
            if (gk + 3 < CIN) {
                v = *(const float4*)(src + gk);
            } else {
                if (gk < CIN)     v.x = src[gk];
                if (gk + 1 < CIN) v.y = src[gk + 1];
                if (gk + 2 < CIN) v.z = src[gk + 2];
            }
            As[kq*4+0][pos] = v.x; As[kq*4+1][pos] = v.y;
            As[kq*4+2][pos] = v.z; As[kq*4+3][pos] = v.w;
        }
        // stage B: 32 o x 32 k in one pass
        {
            int o = t >> 3, kq = t & 7;
            int gk = kb + kq * 4;
            const float* src = W + (size_t)o * CIN;
            float4 v = {0.f, 0.f, 0.f, 0.f};
            if (gk + 3 < CIN) {
                v = *(const float4*)(src + gk);
            } else {
                if (gk < CIN)     v.x = src[gk];
                if (gk + 1 < CIN) v.y = src[gk + 1];
                if (gk + 2 < CIN) v.z = src[gk + 2];
            }
            Bs[kq*4+0][o] = v.x; Bs[kq*4+1][o] = v.y;
            Bs[kq*4+2][o] = v.z; Bs[kq*4+3][o] = v.w;
        }
        __syncthreads();
#pragma unroll 8
        for (int kk = 0; kk < 32; ++kk) {
            float4 a = *(const float4*)&As[kk][tl * 4];
            float4 b = *(const float4*)&Bs[kk][to * 4];
            float av[4] = {a.x, a.y, a.z, a.w};
            float bv[4] = {b.x, b.y, b.z, b.w};
#pragma unroll
            for (int oi = 0; oi < 4; ++oi)
#pragma unroll
                for (int p = 0; p < 4; ++p) acc[oi][p] += av[p] * bv[oi];
        }
    }

#pragma unroll
    for (int oi = 0; oi < 4; ++oi) {
        int o = to * 4 + oi;
        float4 v = {acc[oi][0], acc[oi][1], acc[oi][2], acc[oi][3]};
        *(float4*)(P + ((size_t)n * 32 + o) * LL + l0 + tl * 4) = v;
    }
}

// ---------------- conv2: k=3 pad=1, 32->16, + bias. Input = lrelu(P+b1) fused; emits BN partials ----------------
__global__ __launch_bounds__(256) void k_conv2(const float* __restrict__ P,
                                               const float* __restrict__ b1, const float* __restrict__ W,
                                               const float* __restrict__ bias, float* __restrict__ out,
                                               float* __restrict__ part) {
    __shared__ __align__(16) float Xs[32][264];
    __shared__ __align__(16) float Ws[16][32][4];
    __shared__ float reds[16][33], redq[16][33];
    const int t = threadIdx.x;
    const int bid = blockIdx.x;
    const int n = bid >> 1, l0 = (bid & 1) * 256;
    for (int idx = t; idx < 32 * 258; idx += 256) {
        int i = idx / 258, j = idx % 258;
        int gl = l0 - 1 + j;
        float v = 0.f;
        if (gl >= 0 && gl < LL) {
            size_t off = ((size_t)n * 32 + i) * LL + gl;
            v = lrelu(P[off] + b1[i]);
        }
        Xs[i][j] = v;
    }
    for (int idx = t; idx < 1536; idx += 256) {
        int o = idx / 96, r = idx % 96;
        Ws[o][r / 3][r % 3] = W[idx];
    }
    __syncthreads();
    const int tx = t & 31, ty = t >> 5;
    float acc[2][8];
#pragma unroll
    for (int q = 0; q < 2; ++q)
#pragma unroll
        for (int p = 0; p < 8; ++p) acc[q][p] = 0.f;
    for (int i = 0; i < 32; ++i) {
        float4 a0 = *(const float4*)&Xs[i][tx*8];
        float4 a1 = *(const float4*)&Xs[i][tx*8+4];
        float4 a2 = *(const float4*)&Xs[i][tx*8+8];
        float a[12] = {a0.x,a0.y,a0.z,a0.w,a1.x,a1.y,a1.z,a1.w,a2.x,a2.y,a2.z,a2.w};
#pragma unroll
        for (int q = 0; q < 2; ++q) {
            float4 b = *(const float4*)&Ws[ty*2+q][i][0];
#pragma unroll
            for (int p = 0; p < 8; ++p)
                acc[q][p] += a[p]*b.x + a[p+1]*b.y + a[p+2]*b.z;
        }
    }
#pragma unroll
    for (int q = 0; q < 2; ++q) {
        int o = ty*2+q; float bb = bias[o];
        float s = 0.f, sq = 0.f;
#pragma unroll
        for (int h = 0; h < 2; ++h) {
            float4 v;
            v.x = acc[q][h*4+0] + bb; v.y = acc[q][h*4+1] + bb;
            v.z = acc[q][h*4+2] + bb; v.w = acc[q][h*4+3] + bb;
            s += v.x + v.y + v.z + v.w;
            sq += v.x*v.x + v.y*v.y + v.z*v.z + v.w*v.w;
            *(float4*)(out + ((size_t)n*16 + o)*LL + l0 + tx*8 + h*4) = v;
        }
        reds[o][tx] = s;
        redq[o][tx] = sq;
    }
    __syncthreads();
    if (t < 16) {
        float s = 0.f, sq = 0.f;
#pragma unroll
        for (int x = 0; x < 32; ++x) { s += reds[t][x]; sq += redq[t][x]; }
        part[((size_t)t * 512 + bid) * 2] = s;
        part[((size_t)t * 512 + bid) * 2 + 1] = sq;
    }
}

// ---------------- BN final: reduce S slices per channel ----------------
__global__ void k_bnfinal(const float* __restrict__ part, const float* __restrict__ g,
                          const float* __restrict__ b, int C, int S, float* __restrict__ ss) {
    int ch = threadIdx.x;
    if (ch >= C) return;
    float s = 0.f, q = 0.f;
    for (int j = 0; j < S; ++j) { s += part[((size_t)ch*S + j)*2]; q += part[((size_t)ch*S + j)*2 + 1]; }
    float mean = s * (1.f/131072.f);
    float var = q * (1.f/131072.f) - mean*mean;
    float sc = g[ch] / sqrtf(var + 1e-5f);
    ss[ch] = sc;
    ss[C + ch] = b[ch] - mean * sc;
}

__global__ __launch_bounds__(256) void k_bnapply(const float* __restrict__ src, const float* __restrict__ ss,
        int C, float* __restrict__ dst, int act, int total4) {
    int i4 = blockIdx.x * 256 + threadIdx.x;
    if (i4 >= total4) return;
    int i = i4 << 2;
    int ch = (i >> 9) % C;
    float sc = ss[ch], sh = ss[C + ch];
    float4 v = reinterpret_cast<const float4*>(src)[i4];
    v.x = v.x*sc + sh; v.y = v.y*sc + sh; v.z = v.z*sc + sh; v.w = v.w*sc + sh;
    if (act) { v.x = lrelu(v.x); v.y = lrelu(v.y); v.z = lrelu(v.z); v.w = lrelu(v.w); }
    reinterpret_cast<float4*>(dst)[i4] = v;
}

// ---------------- m_conv1 v6: k=7 pad=3, 128->32. K-split x2, 8 half-stages, LDS dbuf, coalesced NZ staging ----------------
__global__ __launch_bounds__(256) void k_mconv1(const float* __restrict__ C16, const float* __restrict__ NZ,
        const float* __restrict__ PC, const float* __restrict__ W,
        float* __restrict__ out0, float* __restrict__ out1) {
    __shared__ __align__(16) float Gs[2][8][268];
    __shared__ __align__(16) float Ws[2][32][8][8];
    const int t = threadIdx.x;
    const int n = blockIdx.x >> 2, l0 = ((blockIdx.x >> 1) & 1) * 256, z = blockIdx.x & 1;
    const int tx = t & 31, ty = t >> 5;
    float acc[4][8];
#pragma unroll
    for (int q = 0; q < 4; ++q)
#pragma unroll
        for (int p = 0; p < 8; ++p) acc[q][p] = 0.f;

    float4 ga0, ga1, gb0, gb1;
    float wpf[8];
    const int gl1 = l0 - 3 + t;
    const bool ok1 = (gl1 >= 0 && gl1 < LL);
    const int gl2 = l0 + 253 + t;
    const bool ok2 = (t < 6) && (gl2 < LL);

    auto LOADG = [&](int hh) {
        const float4 f4z = {0.f, 0.f, 0.f, 0.f};
        ga0 = f4z; ga1 = f4z; gb0 = f4z; gb1 = f4z;
        if (z == 0 && hh < 2) {
            const float* base = C16 + ((size_t)n * 16 + hh * 8) * LL;
            if (ok1) {
                const float* p = base + gl1;
                ga0.x = p[0];      ga0.y = p[LL];     ga0.z = p[2*LL];  ga0.w = p[3*LL];
                ga1.x = p[4*LL];   ga1.y = p[5*LL];   ga1.z = p[6*LL];  ga1.w = p[7*LL];
            }
            if (ok2) {
                const float* p = base + gl2;
                gb0.x = p[0];      gb0.y = p[LL];     gb0.z = p[2*LL];  gb0.w = p[3*LL];
                gb1.x = p[4*LL];   gb1.y = p[5*LL];   gb1.z = p[6*LL];  gb1.w = p[7*LL];
            }
        } else {
            const int nzc = z * 64 + hh * 8 - 16;
            if (ok1) {
                const float* p = NZ + ((size_t)n * LL + gl1) * 112 + nzc;
                ga0 = *(const float4*)p;
                ga1 = *(const float4*)(p + 4);
            }
            if (ok2) {
                const float* p = NZ + ((size_t)n * LL + gl2) * 112 + nzc;
                gb0 = *(const float4*)p;
                gb1 = *(const float4*)(p + 4);
            }
        }
    };
    auto WRITEG = [&](int bb) {
        Gs[bb][0][t] = ga0.x; Gs[bb][1][t] = ga0.y; Gs[bb][2][t] = ga0.z; Gs[bb][3][t] = ga0.w;
        Gs[bb][4][t] = ga1.x; Gs[bb][5][t] = ga1.y; Gs[bb][6][t] = ga1.z; Gs[bb][7][t] = ga1.w;
        if (t < 6) {
            Gs[bb][0][256+t] = gb0.x; Gs[bb][1][256+t] = gb0.y; Gs[bb][2][256+t] = gb0.z; Gs[bb][3][256+t] = gb0.w;
            Gs[bb][4][256+t] = gb1.x; Gs[bb][5][256+t] = gb1.y; Gs[bb][6][256+t] = gb1.z; Gs[bb][7][256+t] = gb1.w;
        }
    };
    auto LOADW = [&](int hh) {
        const int b7 = (z * 64 + hh * 8) * 7;
#pragma unroll
        for (int p = 0; p < 8; ++p) {
            int idx = p * 256 + t;
            int k = idx & 7, ci = (idx >> 3) & 7, o = idx >> 6;
            wpf[p] = (k < 7) ? W[(size_t)o * 896 + b7 + ci * 7 + k] : 0.f;
        }
    };
    auto WRITEW = [&](int bb) {
#pragma unroll
        for (int p = 0; p < 8; ++p) {
            int idx = p * 256 + t;
            int k = idx & 7;
            if (k < 7) {
                int ci = (idx >> 3) & 7, o = idx >> 6;
                Ws[bb][o][ci][k] = wpf[p];
            }
        }
    };

    LOADG(0);
    LOADW(0);
    WRITEG(0);
    WRITEW(0);
    __syncthreads();

    for (int h = 0; h < 8; ++h) {
        const int hb = h & 1;
        if (h < 7) {
            LOADG(h + 1);
            LOADW(h + 1);
        }
        for (int ci = 0; ci < 8; ++ci) {
            float4 a0 = *(const float4*)&Gs[hb][ci][tx*4];
            float4 a1 = *(const float4*)&Gs[hb][ci][tx*4+4];
            float4 a2 = *(const float4*)&Gs[hb][ci][tx*4+8];
            float4 a3 = *(const float4*)&Gs[hb][ci][128+tx*4];
            float4 a4 = *(const float4*)&Gs[hb][ci][128+tx*4+4];
            float4 a5 = *(const float4*)&Gs[hb][ci][128+tx*4+8];
            float aA[12] = {a0.x,a0.y,a0.z,a0.w,a1.x,a1.y,a1.z,a1.w,a2.x,a2.y,a2.z,a2.w};
            float aB[12] = {a3.x,a3.y,a3.z,a3.w,a4.x,a4.y,a4.z,a4.w,a5.x,a5.y,a5.z,a5.w};
#pragma unroll
            for (int q = 0; q < 4; ++q) {
                float4 b0 = *(const float4*)&Ws[hb][ty*4+q][ci][0];
                float4 b1 = *(const float4*)&Ws[hb][ty*4+q][ci][4];
                float b[7] = {b0.x,b0.y,b0.z,b0.w,b1.x,b1.y,b1.z};
#pragma unroll
                for (int p = 0; p < 4; ++p) {
#pragma unroll
                    for (int k = 0; k < 7; ++k) {
                        acc[q][p]   += aA[p+k]*b[k];
                        acc[q][4+p] += aB[p+k]*b[k];
                    }
                }
            }
        }
        if (h < 7) {
            const int nb = hb ^ 1;
            WRITEG(nb);
            WRITEW(nb);
            __syncthreads();
        }
    }

    float* out = z ? out1 : out0;
#pragma unroll
    for (int q = 0; q < 4; ++q) {
        int o = ty*4 + q;
        float4 p0 = {0.f,0.f,0.f,0.f}, p1 = {0.f,0.f,0.f,0.f};
        if (z == 0) {
            p0 = *(const float4*)(PC + o*LL + l0 + tx*4);
            p1 = *(const float4*)(PC + o*LL + l0 + 128 + tx*4);
        }
        float4 v0 = {acc[q][0]+p0.x, acc[q][1]+p0.y, acc[q][2]+p0.z, acc[q][3]+p0.w};
        float4 v1 = {acc[q][4]+p1.x, acc[q][5]+p1.y, acc[q][6]+p1.z, acc[q][7]+p1.w};
        *(float4*)(out + ((size_t)n*32 + o)*LL + l0 + tx*4) = v0;
        *(float4*)(out + ((size_t)n*32 + o)*LL + l0 + 128 + tx*4) = v1;
    }
}

// ---------------- m_conv2: k=3 pad=1, 32->8, + bias. Input = lrelu(P0+P1) fused; emits BN partials ----------------
__global__ __launch_bounds__(256) void k_mconv2(const float* __restrict__ P0, const float* __restrict__ P1,
        const float* __restrict__ W, const float* __restrict__ bias, float* __restrict__ out,
        float* __restrict__ part) {
    __shared__ __align__(16) float Xs[32][264];
    __shared__ __align__(16) float Ws[8][32][4];
    __shared__ float reds[8][33], redq[8][33];
    const int t = threadIdx.x;
    const int bid = blockIdx.x;
    const int n = bid >> 1, l0 = (bid & 1) * 256;
    for (int idx = t; idx < 32 * 258; idx += 256) {
        int i = idx / 258, j = idx % 258;
        int gl = l0 - 1 + j;
        float v = 0.f;
        if (gl >= 0 && gl < LL) {
            size_t off = ((size_t)n * 32 + i) * LL + gl;
            v = lrelu(P0[off] + P1[off]);
        }
        Xs[i][j] = v;
    }
    for (int idx = t; idx < 768; idx += 256) {
        int o = idx / 96, r = idx % 96;
        Ws[o][r / 3][r % 3] = W[idx];
    }
    __syncthreads();
    const int tx = t & 31, ty = t >> 5;
    float acc[8];
#pragma unroll
    for (int p = 0; p < 8; ++p) acc[p] = 0.f;
    for (int i = 0; i < 32; ++i) {
        float4 a0 = *(const float4*)&Xs[i][tx*8];
        float4 a1 = *(const float4*)&Xs[i][tx*8+4];
        float4 a2 = *(const float4*)&Xs[i][tx*8+8];
        float a[12] = {a0.x,a0.y,a0.z,a0.w,a1.x,a1.y,a1.z,a1.w,a2.x,a2.y,a2.z,a2.w};
        float4 b = *(const float4*)&Ws[ty][i][0];
#pragma unroll
        for (int p = 0; p < 8; ++p)
            acc[p] += a[p]*b.x + a[p+1]*b.y + a[p+2]*b.z;
    }
    float bb = bias[ty];
    float s = 0.f, sq = 0.f;
#pragma unroll
    for (int h = 0; h < 2; ++h) {
        float4 v;
        v.x = acc[h*4+0] + bb; v.y = acc[h*4+1] + bb;
        v.z = acc[h*4+2] + bb; v.w = acc[h*4+3] + bb;
        s += v.x + v.y + v.z + v.w;
        sq += v.x*v.x + v.y*v.y + v.z*v.z + v.w*v.w;
        *(float4*)(out + ((size_t)n*8 + ty)*LL + l0 + tx*8 + h*4) = v;
    }
    reds[ty][tx] = s;
    redq[ty][tx] = sq;
    __syncthreads();
    if (t < 8) {
        float ss = 0.f, qq = 0.f;
#pragma unroll
        for (int x = 0; x < 32; ++x) { ss += reds[t][x]; qq += redq[t][x]; }
        part[((size_t)t * 512 + bid) * 2] = ss;
        part[((size_t)t * 512 + bid) * 2 + 1] = qq;
    }
}

// ---------------- linear 4096x4096 v4: 128x128 tile, BK=16, 8x8 micro, z=16, no prefetch ----------------
__global__ __launch_bounds__(256) void k_lin(const float* __restrict__ A, const float* __restrict__ B,
                                             float* __restrict__ part) {
    __shared__ __align__(16) float As[16][132];
    __shared__ __align__(16) float Bs[16][132];
    const int t = threadIdx.x;
    const int bid = blockIdx.x;
    const int xcd = bid & 7, j = bid >> 3;
    const int z = j >> 3;
    const int m0 = ((j >> 2) & 1) * 128;
    const int f0 = (xcd * 4 + (j & 3)) * 128;
    const int k0base = z * 256;
    const int sar = t & 127, saq = t >> 7;
    const int sbr = t >> 4, sbq = t & 15;
    const int mq = (t & 15) * 4, fq = (t >> 4) * 4;

    float acc[8][8];
#pragma unroll
    for (int i = 0; i < 8; ++i)
#pragma unroll
        for (int q = 0; q < 8; ++q) acc[i][q] = 0.f;

    for (int it = 0; it < 16; ++it) {
        const int k0 = k0base + it * 16;
        {
            const float* pA = A + (size_t)(m0 + sar) * 4096 + k0 + saq * 8;
            float4 a0 = *(const float4*)(pA);
            float4 a1 = *(const float4*)(pA + 4);
            const float* pB = B + (size_t)(k0 + sbr) * 4096 + f0 + sbq * 8;
            float4 b0 = *(const float4*)(pB);
            float4 b1 = *(const float4*)(pB + 4);
            As[saq*8+0][sar] = a0.x; As[saq*8+1][sar] = a0.y; As[saq*8+2][sar] = a0.z; As[saq*8+3][sar] = a0.w;
            As[saq*8+4][sar] = a1.x; As[saq*8+5][sar] = a1.y; As[saq*8+6][sar] = a1.z; As[saq*8+7][sar] = a1.w;
            *(float4*)&Bs[sbr][sbq*8] = b0;
            *(float4*)&Bs[sbr][sbq*8+4] = b1;
        }
        __syncthreads();
#pragma unroll
        for (int kk = 0; kk < 16; ++kk) {
            float4 a0 = *(const float4*)&As[kk][mq];
            float4 a1 = *(const float4*)&As[kk][mq + 64];
            float4 b0 = *(const float4*)&Bs[kk][fq];
            float4 b1 = *(const float4*)&Bs[kk][fq + 64];
            float av[8] = {a0.x,a0.y,a0.z,a0.w,a1.x,a1.y,a1.z,a1.w};
            float bv[8] = {b0.x,b0.y,b0.z,b0.w,b1.x,b1.y,b1.z,b1.w};
#pragma unroll
            for (int i = 0; i < 8; ++i)
#pragma unroll
                for (int q = 0; q < 8; ++q) acc[i][q] += av[i] * bv[q];
        }
        __syncthreads();
    }

#pragma unroll
    for (int i = 0; i < 8; ++i) {
        int m = m0 + mq + (i & 3) + (i >> 2) * 64;
        float4 v0 = {acc[i][0], acc[i][1], acc[i][2], acc[i][3]};
        float4 v1 = {acc[i][4], acc[i][5], acc[i][6], acc[i][7]};
        *(float4*)(part + ((size_t)z * 256 + m) * 4096 + f0 + fq) = v0;
        *(float4*)(part + ((size_t)z * 256 + m) * 4096 + f0 + fq + 64) = v1;
    }
}

// sum 16 K-partials + bias + lrelu
__global__ __launch_bounds__(256) void k_linred(const float* __restrict__ part, const float* __restrict__ bias,
        float* __restrict__ out) {
    int i4 = blockIdx.x*256 + threadIdx.x;   // < 262144
    int i = i4 << 2;
    int f = i & 4095;
    float4 s = *(const float4*)(bias + f);
#pragma unroll
    for (int zz = 0; zz < 16; ++zz) {
        float4 p = ((const float4*)(part + (size_t)zz * 1048576))[i4];
        s.x += p.x; s.y += p.y; s.z += p.z; s.w += p.w;
    }
    float4 r;
    r.x = lrelu(s.x); r.y = lrelu(s.y); r.z = lrelu(s.z); r.w = lrelu(s.w);
    ((float4*)out)[i4] = r;
}

// ---------------- heads: [4096x512 | 4096x256], split-K (16), no prefetch ----------------
__global__ __launch_bounds__(256) void k_heads(const float* __restrict__ A, const float* __restrict__ CW,
        const float* __restrict__ SW, float* __restrict__ part) {
    __shared__ __align__(16) float As[32][36];
    __shared__ __align__(16) float Bs[32][132];
    const int t = threadIdx.x;
    const int m0 = blockIdx.x * 32, f0 = blockIdx.y * 128, z = blockIdx.z;
    const float* B; int ldb, fb;
    if (f0 < 512) { B = CW; ldb = 512; fb = f0; } else { B = SW; ldb = 256; fb = f0 - 512; }
    const int tm = t & 7, tf = t >> 3;
    const int mi = t >> 3, kq = t & 7;
    float acc[4][4];
#pragma unroll
    for (int pm = 0; pm < 4; ++pm)
#pragma unroll
        for (int pf = 0; pf < 4; ++pf) acc[pm][pf] = 0.f;
    for (int k0 = z * 256; k0 < z * 256 + 256; k0 += 32) {
        float4 av = *(const float4*)(A + (size_t)(m0 + mi) * 4096 + k0 + kq * 4);
        As[kq*4+0][mi] = av.x; As[kq*4+1][mi] = av.y; As[kq*4+2][mi] = av.z; As[kq*4+3][mi] = av.w;
#pragma unroll
        for (int pass = 0; pass < 4; ++pass) {
            int fi = pass * 32 + kq * 4;
            *(float4*)&Bs[mi][fi] = *(const float4*)(B + (size_t)(k0 + mi) * ldb + fb + fi);
        }
        __syncthreads();
#pragma unroll 8
        for (int kk = 0; kk < 32; ++kk) {
            float4 a = *(const float4*)&As[kk][tm * 4];
            float4 b = *(const float4*)&Bs[kk][tf * 4];
            float avv[4] = {a.x,a.y,a.z,a.w};
            float bvv[4] = {b.x,b.y,b.z,b.w};
#pragma unroll
            for (int pm = 0; pm < 4; ++pm)
#pragma unroll
                for (int pf = 0; pf < 4; ++pf) acc[pm][pf] += avv[pm]*bvv[pf];
        }
        __syncthreads();
    }
#pragma unroll
    for (int pm = 0; pm < 4; ++pm) {
        float4 v = {acc[pm][0], acc[pm][1], acc[pm][2], acc[pm][3]};
        *(float4*)(part + ((size_t)z * 256 + m0 + tm * 4 + pm) * 768 + f0 + tf * 4) = v;
    }
}

// ---------------- assemble (fused headred) + gumbel softmax(hard) ----------------
__global__ __launch_bounds__(256) void k_assemble(const float* __restrict__ part, const float* __restrict__ cb,
        const float* __restrict__ sb, const float* __restrict__ gum, float* __restrict__ out) {
    __shared__ float buf[768];
    const int n = blockIdx.x;
    const int t = threadIdx.x;
#pragma unroll
    for (int rep = 0; rep < 3; ++rep) {
        int f = rep * 256 + t;
        float s = 0.f;
#pragma unroll
        for (int ks = 0; ks < 16; ++ks) s += part[((size_t)(ks * 256 + n)) * 768 + f];
        s += (f < 512) ? cb[f] : sb[f - 512];
        buf[f] = s;
    }
    __syncthreads();
    if (t >= 128) return;
    const int b = t;
    const float* cp = buf;
    const float* sp = buf + 512;
    float sl0 = sp[2*b], sl1 = sp[2*b+1];
    int s = sl1 > sl0 ? 1 : 0;
    int prevb = 0;
    if (b > 0) prevb = (sp[2*b-1] > sp[2*b-2]) ? 1 : 0;
    bool body = (s == 1) && (b < 127);
    bool tail = ((s == 1) && (b == 127)) || ((s == 0) && (prevb == 1));
    float c0a = cp[4*b], c0b = cp[4*b+1], c1a = cp[4*b+2], c1b = cp[4*b+3];
    bool cA = c0b > c0a, cB = c1b > c1a;
    float rows[4][3];
    if (body || tail)      { rows[0][0]=sl0; rows[0][1]=0.f; rows[0][2]=sl1; }
    else if (cA)           { rows[0][0]=c0a; rows[0][1]=c0b; rows[0][2]=0.f; }
    else                   { rows[0][0]=1.f; rows[0][1]=0.f; rows[0][2]=0.f; }
    if (body)              { rows[1][0]=0.f; rows[1][1]=0.f; rows[1][2]=1.f; }
    else                   { rows[1][0]=1.f; rows[1][1]=0.f; rows[1][2]=0.f; }
    if (body)              { rows[2][0]=0.f; rows[2][1]=0.f; rows[2][2]=1.f; }
    else if (cB)           { rows[2][0]=c1a; rows[2][1]=c1b; rows[2][2]=0.f; }
    else                   { rows[2][0]=1.f; rows[2][1]=0.f; rows[2][2]=0.f; }
    rows[3][0]=rows[1][0]; rows[3][1]=rows[1][1]; rows[3][2]=rows[1][2];
#pragma unroll
    for (int r = 0; r < 4; ++r) {
        int l = 4*b + r;
        const float* u = gum + ((size_t)n*512 + l)*3;
        float g0 = -logf(-logf(u[0]+1e-10f)+1e-10f);
        float g1 = -logf(-logf(u[1]+1e-10f)+1e-10f);
        float g2 = -logf(-logf(u[2]+1e-10f)+1e-10f);
        float t0 = rows[r][0]+g0, t1 = rows[r][1]+g1, t2 = rows[r][2]+g2;
        int am = 0; float mv = t0;
        if (t1 > mv) { am = 1; mv = t1; }
        if (t2 > mv) { am = 2; mv = t2; }
        float e0 = expf(t0-mv), e1 = expf(t1-mv), e2 = expf(t2-mv);
        float ssum = e0+e1+e2;
        float y0 = e0/ssum, y1 = e1/ssum, y2 = e2/ssum;
        float* o = out + ((size_t)n*512 + l)*3;
        o[0] = ((am==0?1.f:0.f) + y0) - y0;
        o[1] = ((am==1?1.f:0.f) + y1) - y1;
        o[2] = ((am==2?1.f:0.f) + y2) - y2;
    }
}

extern "C" void kernel_launch(void* const* d_in, const int* in_sizes, int n_in,
                              void* d_out, int out_size, void* d_ws, size_t ws_size,
                              hipStream_t stream) {
    const float* noise   = (const float*)d_in[0];
    const float* cond    = (const float*)d_in[1];
    const float* gumbel  = (const float*)d_in[2];
    const float* ext_w1  = (const float*)d_in[3];
    const float* ext_b1  = (const float*)d_in[4];
    const float* ext_w2  = (const float*)d_in[5];
    const float* ext_b2  = (const float*)d_in[6];
    const float* ext_bng = (const float*)d_in[7];
    const float* ext_bnb = (const float*)d_in[8];
    const float* m_w1    = (const float*)d_in[9];
    const float* m_b1    = (const float*)d_in[10];
    const float* m_w2    = (const float*)d_in[11];
    const float* m_b2    = (const float*)d_in[12];
    const float* m_bng   = (const float*)d_in[13];
    const float* m_bnb   = (const float*)d_in[14];
    const float* lin_w   = (const float*)d_in[15];
    const float* lin_b   = (const float*)d_in[16];
    const float* circ_w  = (const float*)d_in[17];
    const float* circ_b  = (const float*)d_in[18];
    const float* slid_w  = (const float*)d_in[19];
    const float* slid_b  = (const float*)d_in[20];

    float* genout  = (float*)d_out;                       // [256][512][3]
    float* condout = (float*)d_out + 256*512*3;           // [256][16][512]

    float* w     = (float*)d_ws;
    float* ws0   = w;                  // 16,777,216 floats: conv1 out / mconv1 partials / k_lin partials
    float* y2    = ws0 + 16777216;     // 2097152 (h2 raw / flat_in)
    float* posb  = y2 + 2097152;       // 65536
    float* pc    = posb + 65536;       // 16384  (posconv table [32][512])
    float* flatB = pc + 16384;         // 1048576
    float* partH = flatB + 1048576;    // 3145728 (heads partials z=16)
    float* statA = partH + 3145728;    // 16384 (conv2 BN partials: 16ch x 512 x 2)
    float* ssA   = statA + 16384;      // 64
    float* statB = ssA + 64;           // 8192 (mconv2 BN partials: 8ch x 512 x 2)
    float* ssB   = statB + 8192;       // 64

    k_pos<<<256, 256, 0, stream>>>(posb);
    k_posconv<<<512, 256, 0, stream>>>(posb, m_w1, m_b1, pc);
    k_conv1<<<1024, 256, 0, stream>>>(cond, ext_w1, ws0);
    k_conv2<<<512, 256, 0, stream>>>(ws0, ext_b1, ext_w2, ext_b2, y2, statA);
    k_bnfinal<<<1, 64, 0, stream>>>(statA, ext_bng, ext_bnb, 16, 512, ssA);
    k_bnapply<<<2048, 256, 0, stream>>>(y2, ssA, 16, condout, 0, 524288);
    k_mconv1<<<1024, 256, 0, stream>>>(condout, noise, pc, m_w1, ws0, ws0 + 4194304);
    k_mconv2<<<512, 256, 0, stream>>>(ws0, ws0 + 4194304, m_w2, m_b2, y2, statB);
    k_bnfinal<<<1, 64, 0, stream>>>(statB, m_bng, m_bnb, 8, 512, ssB);
    k_bnapply<<<1024, 256, 0, stream>>>(y2, ssB, 8, y2, 1, 262144);
    k_lin<<<1024, 256, 0, stream>>>(y2, lin_w, ws0);
    k_linred<<<1024, 256, 0, stream>>>(ws0, lin_b, flatB);
    k_heads<<<dim3(8,6,16), 256, 0, stream>>>(flatB, circ_w, slid_w, partH);
    k_assemble<<<256, 256, 0, stream>>>(partH, circ_b, slid_b, gumbel, genout);
}

// Round 16
// 499.013 us; speedup vs baseline: 1.3779x; 1.1716x over previous
//
#include <hip/hip_runtime.h>
#include <math.h>

#define NB 256
#define LL 512
#define CIN 514

__device__ __forceinline__ float lrelu(float x) { return x >= 0.f ? x : 0.2f * x; }

// ---------------- positional encoding table [128][512], fp64 math like numpy ----------------
__global__ __launch_bounds__(256) void k_pos(float* __restrict__ pos) {
    int idx = blockIdx.x * 256 + threadIdx.x;   // 65536 total
    int c = idx >> 9, l = idx & 511;
    double e = (double)(2 * (c >> 1)) / 128.0;
    double dv = 1.0 / pow(10000.0, e);
    double a = (double)l * dv;
    pos[idx] = (float)((c & 1) ? cos(a) : sin(a));
}

// ---------------- posconv: PC[o][l] = bias[o] + sum_c sum_k W[o][c][k]*POS[c][l+k-3] ----------------
__global__ __launch_bounds__(256) void k_posconv(const float* __restrict__ POS, const float* __restrict__ W,
                                                 const float* __restrict__ bias, float* __restrict__ PC) {
    const int t = threadIdx.x;
    const int o = blockIdx.x >> 4, l0 = (blockIdx.x & 15) * 32;
    const int l = l0 + (t & 31), cs = t >> 5;
    float acc = 0.f;
    for (int ci = 0; ci < 16; ++ci) {
        int c = cs * 16 + ci;
        float wv[7];
#pragma unroll
        for (int k = 0; k < 7; ++k) wv[k] = W[o * 896 + c * 7 + k];
#pragma unroll
        for (int k = 0; k < 7; ++k) {
            int gl = l + k - 3;
            if (gl >= 0 && gl < LL) acc += wv[k] * POS[c * LL + gl];
        }
    }
    __shared__ float red[8][33];
    red[cs][t & 31] = acc;
    __syncthreads();
    if (cs == 0) {
        float s = bias[o];
#pragma unroll
        for (int j = 0; j < 8; ++j) s += red[j][t & 31];
        PC[o * LL + l0 + (t & 31)] = s;
    }
}

// ---------------- conv1 v7: 1x1, 514->32. Full-K per block, 128-row l-chunks, no partials ----------------
__global__ __launch_bounds__(256, 4) void k_conv1(const float* __restrict__ X, const float* __restrict__ W,
                                                  float* __restrict__ P) {
    __shared__ __align__(16) float As[32][132];
    __shared__ __align__(16) float Bs[32][36];
    const int t = threadIdx.x;
    const int n = blockIdx.x >> 2, l0 = (blockIdx.x & 3) * 128;
    const int tl = t & 31, to = t >> 5;
    const size_t rowbase = (size_t)n * 512 * CIN;

    float acc[4][4];
#pragma unroll
    for (int oi = 0; oi < 4; ++oi)
#pragma unroll
        for (int p = 0; p < 4; ++p) acc[oi][p] = 0.f;

    for (int c = 0; c < 17; ++c) {
        const int kb = c * 32;
        if (c) __syncthreads();
#pragma unroll
        for (int ps = 0; ps < 4; ++ps) {
            int idx = ps * 256 + t;
            int pos = idx >> 3, kq = idx & 7;
            int gk = kb + kq * 4;
            const float* src = X + rowbase + (size_t)(l0 + pos) * CIN;
            float4 v = {0.f, 0.f, 0.f, 0.f};
            if (gk + 3 < CIN) {
                v = *(const float4*)(src + gk);
            } else {
                if (gk < CIN)     v.x = src[gk];
                if (gk + 1 < CIN) v.y = src[gk + 1];
                if (gk + 2 < CIN) v.z = src[gk + 2];
            }
            As[kq*4+0][pos] = v.x; As[kq*4+1][pos] = v.y;
            As[kq*4+2][pos] = v.z; As[kq*4+3][pos] = v.w;
        }
        {
            int o = t >> 3, kq = t & 7;
            int gk = kb + kq * 4;
            const float* src = W + (size_t)o * CIN;
            float4 v = {0.f, 0.f, 0.f, 0.f};
            if (gk + 3 < CIN) {
                v = *(const float4*)(src + gk);
            } else {
                if (gk < CIN)     v.x = src[gk];
                if (gk + 1 < CIN) v.y = src[gk + 1];
                if (gk + 2 < CIN) v.z = src[gk + 2];
            }
            Bs[kq*4+0][o] = v.x; Bs[kq*4+1][o] = v.y;
            Bs[kq*4+2][o] = v.z; Bs[kq*4+3][o] = v.w;
        }
        __syncthreads();
#pragma unroll 8
        for (int kk = 0; kk < 32; ++kk) {
            float4 a = *(const float4*)&As[kk][tl * 4];
            float4 b = *(const float4*)&Bs[kk][to * 4];
            float av[4] = {a.x, a.y, a.z, a.w};
            float bv[4] = {b.x, b.y, b.z, b.w};
#pragma unroll
            for (int oi = 0; oi < 4; ++oi)
#pragma unroll
                for (int p = 0; p < 4; ++p) acc[oi][p] += av[p] * bv[oi];
        }
    }

#pragma unroll
    for (int oi = 0; oi < 4; ++oi) {
        int o = to * 4 + oi;
        float4 v = {acc[oi][0], acc[oi][1], acc[oi][2], acc[oi][3]};
        *(float4*)(P + ((size_t)n * 32 + o) * LL + l0 + tl * 4) = v;
    }
}

// ---------------- conv2: k=3 pad=1, 32->16, + bias. Input = lrelu(P+b1) fused; emits BN partials ----------------
__global__ __launch_bounds__(256) void k_conv2(const float* __restrict__ P,
                                               const float* __restrict__ b1, const float* __restrict__ W,
                                               const float* __restrict__ bias, float* __restrict__ out,
                                               float* __restrict__ part) {
    __shared__ __align__(16) float Xs[32][264];
    __shared__ __align__(16) float Ws[16][32][4];
    __shared__ float reds[16][33], redq[16][33];
    const int t = threadIdx.x;
    const int bid = blockIdx.x;
    const int n = bid >> 1, l0 = (bid & 1) * 256;
    for (int idx = t; idx < 32 * 258; idx += 256) {
        int i = idx / 258, j = idx % 258;
        int gl = l0 - 1 + j;
        float v = 0.f;
        if (gl >= 0 && gl < LL) {
            size_t off = ((size_t)n * 32 + i) * LL + gl;
            v = lrelu(P[off] + b1[i]);
        }
        Xs[i][j] = v;
    }
    for (int idx = t; idx < 1536; idx += 256) {
        int o = idx / 96, r = idx % 96;
        Ws[o][r / 3][r % 3] = W[idx];
    }
    __syncthreads();
    const int tx = t & 31, ty = t >> 5;
    float acc[2][8];
#pragma unroll
    for (int q = 0; q < 2; ++q)
#pragma unroll
        for (int p = 0; p < 8; ++p) acc[q][p] = 0.f;
    for (int i = 0; i < 32; ++i) {
        float4 a0 = *(const float4*)&Xs[i][tx*8];
        float4 a1 = *(const float4*)&Xs[i][tx*8+4];
        float4 a2 = *(const float4*)&Xs[i][tx*8+8];
        float a[12] = {a0.x,a0.y,a0.z,a0.w,a1.x,a1.y,a1.z,a1.w,a2.x,a2.y,a2.z,a2.w};
#pragma unroll
        for (int q = 0; q < 2; ++q) {
            float4 b = *(const float4*)&Ws[ty*2+q][i][0];
#pragma unroll
            for (int p = 0; p < 8; ++p)
                acc[q][p] += a[p]*b.x + a[p+1]*b.y + a[p+2]*b.z;
        }
    }
#pragma unroll
    for (int q = 0; q < 2; ++q) {
        int o = ty*2+q; float bb = bias[o];
        float s = 0.f, sq = 0.f;
#pragma unroll
        for (int h = 0; h < 2; ++h) {
            float4 v;
            v.x = acc[q][h*4+0] + bb; v.y = acc[q][h*4+1] + bb;
            v.z = acc[q][h*4+2] + bb; v.w = acc[q][h*4+3] + bb;
            s += v.x + v.y + v.z + v.w;
            sq += v.x*v.x + v.y*v.y + v.z*v.z + v.w*v.w;
            *(float4*)(out + ((size_t)n*16 + o)*LL + l0 + tx*8 + h*4) = v;
        }
        reds[o][tx] = s;
        redq[o][tx] = sq;
    }
    __syncthreads();
    if (t < 16) {
        float s = 0.f, sq = 0.f;
#pragma unroll
        for (int x = 0; x < 32; ++x) { s += reds[t][x]; sq += redq[t][x]; }
        part[((size_t)t * 512 + bid) * 2] = s;
        part[((size_t)t * 512 + bid) * 2 + 1] = sq;
    }
}

// ---------------- BN final v2: parallel reduce S slices per channel (grid = C, 256 thr) ----------------
__global__ __launch_bounds__(256) void k_bnfinal(const float* __restrict__ part, const float* __restrict__ g,
                                                 const float* __restrict__ b, int C, int S, float* __restrict__ ss) {
    const int ch = blockIdx.x;
    const int t = threadIdx.x;
    float s = 0.f, q = 0.f;
    for (int j = t; j < S; j += 256) {
        float2 v = *(const float2*)(part + ((size_t)ch * S + j) * 2);
        s += v.x; q += v.y;
    }
    __shared__ float rs[256], rq[256];
    rs[t] = s; rq[t] = q;
    __syncthreads();
    for (int off = 128; off > 0; off >>= 1) {
        if (t < off) { rs[t] += rs[t + off]; rq[t] += rq[t + off]; }
        __syncthreads();
    }
    if (t == 0) {
        float mean = rs[0] * (1.f/131072.f);
        float var = rq[0] * (1.f/131072.f) - mean * mean;
        float sc = g[ch] / sqrtf(var + 1e-5f);
        ss[ch] = sc;
        ss[C + ch] = b[ch] - mean * sc;
    }
}

__global__ __launch_bounds__(256) void k_bnapply(const float* __restrict__ src, const float* __restrict__ ss,
        int C, float* __restrict__ dst, int act, int total4) {
    int i4 = blockIdx.x * 256 + threadIdx.x;
    if (i4 >= total4) return;
    int i = i4 << 2;
    int ch = (i >> 9) % C;
    float sc = ss[ch], sh = ss[C + ch];
    float4 v = reinterpret_cast<const float4*>(src)[i4];
    v.x = v.x*sc + sh; v.y = v.y*sc + sh; v.z = v.z*sc + sh; v.w = v.w*sc + sh;
    if (act) { v.x = lrelu(v.x); v.y = lrelu(v.y); v.z = lrelu(v.z); v.w = lrelu(v.w); }
    reinterpret_cast<float4*>(dst)[i4] = v;
}

// ---------------- m_conv1 v6: k=7 pad=3, 128->32. K-split x2, 8 half-stages, LDS dbuf, coalesced NZ staging ----------------
__global__ __launch_bounds__(256) void k_mconv1(const float* __restrict__ C16, const float* __restrict__ NZ,
        const float* __restrict__ PC, const float* __restrict__ W,
        float* __restrict__ out0, float* __restrict__ out1) {
    __shared__ __align__(16) float Gs[2][8][268];
    __shared__ __align__(16) float Ws[2][32][8][8];
    const int t = threadIdx.x;
    const int n = blockIdx.x >> 2, l0 = ((blockIdx.x >> 1) & 1) * 256, z = blockIdx.x & 1;
    const int tx = t & 31, ty = t >> 5;
    float acc[4][8];
#pragma unroll
    for (int q = 0; q < 4; ++q)
#pragma unroll
        for (int p = 0; p < 8; ++p) acc[q][p] = 0.f;

    float4 ga0, ga1, gb0, gb1;
    float wpf[8];
    const int gl1 = l0 - 3 + t;
    const bool ok1 = (gl1 >= 0 && gl1 < LL);
    const int gl2 = l0 + 253 + t;
    const bool ok2 = (t < 6) && (gl2 < LL);

    auto LOADG = [&](int hh) {
        const float4 f4z = {0.f, 0.f, 0.f, 0.f};
        ga0 = f4z; ga1 = f4z; gb0 = f4z; gb1 = f4z;
        if (z == 0 && hh < 2) {
            const float* base = C16 + ((size_t)n * 16 + hh * 8) * LL;
            if (ok1) {
                const float* p = base + gl1;
                ga0.x = p[0];      ga0.y = p[LL];     ga0.z = p[2*LL];  ga0.w = p[3*LL];
                ga1.x = p[4*LL];   ga1.y = p[5*LL];   ga1.z = p[6*LL];  ga1.w = p[7*LL];
            }
            if (ok2) {
                const float* p = base + gl2;
                gb0.x = p[0];      gb0.y = p[LL];     gb0.z = p[2*LL];  gb0.w = p[3*LL];
                gb1.x = p[4*LL];   gb1.y = p[5*LL];   gb1.z = p[6*LL];  gb1.w = p[7*LL];
            }
        } else {
            const int nzc = z * 64 + hh * 8 - 16;
            if (ok1) {
                const float* p = NZ + ((size_t)n * LL + gl1) * 112 + nzc;
                ga0 = *(const float4*)p;
                ga1 = *(const float4*)(p + 4);
            }
            if (ok2) {
                const float* p = NZ + ((size_t)n * LL + gl2) * 112 + nzc;
                gb0 = *(const float4*)p;
                gb1 = *(const float4*)(p + 4);
            }
        }
    };
    auto WRITEG = [&](int bb) {
        Gs[bb][0][t] = ga0.x; Gs[bb][1][t] = ga0.y; Gs[bb][2][t] = ga0.z; Gs[bb][3][t] = ga0.w;
        Gs[bb][4][t] = ga1.x; Gs[bb][5][t] = ga1.y; Gs[bb][6][t] = ga1.z; Gs[bb][7][t] = ga1.w;
        if (t < 6) {
            Gs[bb][0][256+t] = gb0.x; Gs[bb][1][256+t] = gb0.y; Gs[bb][2][256+t] = gb0.z; Gs[bb][3][256+t] = gb0.w;
            Gs[bb][4][256+t] = gb1.x; Gs[bb][5][256+t] = gb1.y; Gs[bb][6][256+t] = gb1.z; Gs[bb][7][256+t] = gb1.w;
        }
    };
    auto LOADW = [&](int hh) {
        const int b7 = (z * 64 + hh * 8) * 7;
#pragma unroll
        for (int p = 0; p < 8; ++p) {
            int idx = p * 256 + t;
            int k = idx & 7, ci = (idx >> 3) & 7, o = idx >> 6;
            wpf[p] = (k < 7) ? W[(size_t)o * 896 + b7 + ci * 7 + k] : 0.f;
        }
    };
    auto WRITEW = [&](int bb) {
#pragma unroll
        for (int p = 0; p < 8; ++p) {
            int idx = p * 256 + t;
            int k = idx & 7;
            if (k < 7) {
                int ci = (idx >> 3) & 7, o = idx >> 6;
                Ws[bb][o][ci][k] = wpf[p];
            }
        }
    };

    LOADG(0);
    LOADW(0);
    WRITEG(0);
    WRITEW(0);
    __syncthreads();

    for (int h = 0; h < 8; ++h) {
        const int hb = h & 1;
        if (h < 7) {
            LOADG(h + 1);
            LOADW(h + 1);
        }
        for (int ci = 0; ci < 8; ++ci) {
            float4 a0 = *(const float4*)&Gs[hb][ci][tx*4];
            float4 a1 = *(const float4*)&Gs[hb][ci][tx*4+4];
            float4 a2 = *(const float4*)&Gs[hb][ci][tx*4+8];
            float4 a3 = *(const float4*)&Gs[hb][ci][128+tx*4];
            float4 a4 = *(const float4*)&Gs[hb][ci][128+tx*4+4];
            float4 a5 = *(const float4*)&Gs[hb][ci][128+tx*4+8];
            float aA[12] = {a0.x,a0.y,a0.z,a0.w,a1.x,a1.y,a1.z,a1.w,a2.x,a2.y,a2.z,a2.w};
            float aB[12] = {a3.x,a3.y,a3.z,a3.w,a4.x,a4.y,a4.z,a4.w,a5.x,a5.y,a5.z,a5.w};
#pragma unroll
            for (int q = 0; q < 4; ++q) {
                float4 b0 = *(const float4*)&Ws[hb][ty*4+q][ci][0];
                float4 b1 = *(const float4*)&Ws[hb][ty*4+q][ci][4];
                float b[7] = {b0.x,b0.y,b0.z,b0.w,b1.x,b1.y,b1.z};
#pragma unroll
                for (int p = 0; p < 4; ++p) {
#pragma unroll
                    for (int k = 0; k < 7; ++k) {
                        acc[q][p]   += aA[p+k]*b[k];
                        acc[q][4+p] += aB[p+k]*b[k];
                    }
                }
            }
        }
        if (h < 7) {
            const int nb = hb ^ 1;
            WRITEG(nb);
            WRITEW(nb);
            __syncthreads();
        }
    }

    float* out = z ? out1 : out0;
#pragma unroll
    for (int q = 0; q < 4; ++q) {
        int o = ty*4 + q;
        float4 p0 = {0.f,0.f,0.f,0.f}, p1 = {0.f,0.f,0.f,0.f};
        if (z == 0) {
            p0 = *(const float4*)(PC + o*LL + l0 + tx*4);
            p1 = *(const float4*)(PC + o*LL + l0 + 128 + tx*4);
        }
        float4 v0 = {acc[q][0]+p0.x, acc[q][1]+p0.y, acc[q][2]+p0.z, acc[q][3]+p0.w};
        float4 v1 = {acc[q][4]+p1.x, acc[q][5]+p1.y, acc[q][6]+p1.z, acc[q][7]+p1.w};
        *(float4*)(out + ((size_t)n*32 + o)*LL + l0 + tx*4) = v0;
        *(float4*)(out + ((size_t)n*32 + o)*LL + l0 + 128 + tx*4) = v1;
    }
}

// ---------------- m_conv2: k=3 pad=1, 32->8, + bias. Input = lrelu(P0+P1) fused; emits BN partials ----------------
__global__ __launch_bounds__(256) void k_mconv2(const float* __restrict__ P0, const float* __restrict__ P1,
        const float* __restrict__ W, const float* __restrict__ bias, float* __restrict__ out,
        float* __restrict__ part) {
    __shared__ __align__(16) float Xs[32][264];
    __shared__ __align__(16) float Ws[8][32][4];
    __shared__ float reds[8][33], redq[8][33];
    const int t = threadIdx.x;
    const int bid = blockIdx.x;
    const int n = bid >> 1, l0 = (bid & 1) * 256;
    for (int idx = t; idx < 32 * 258; idx += 256) {
        int i = idx / 258, j = idx % 258;
        int gl = l0 - 1 + j;
        float v = 0.f;
        if (gl >= 0 && gl < LL) {
            size_t off = ((size_t)n * 32 + i) * LL + gl;
            v = lrelu(P0[off] + P1[off]);
        }
        Xs[i][j] = v;
    }
    for (int idx = t; idx < 768; idx += 256) {
        int o = idx / 96, r = idx % 96;
        Ws[o][r / 3][r % 3] = W[idx];
    }
    __syncthreads();
    const int tx = t & 31, ty = t >> 5;
    float acc[8];
#pragma unroll
    for (int p = 0; p < 8; ++p) acc[p] = 0.f;
    for (int i = 0; i < 32; ++i) {
        float4 a0 = *(const float4*)&Xs[i][tx*8];
        float4 a1 = *(const float4*)&Xs[i][tx*8+4];
        float4 a2 = *(const float4*)&Xs[i][tx*8+8];
        float a[12] = {a0.x,a0.y,a0.z,a0.w,a1.x,a1.y,a1.z,a1.w,a2.x,a2.y,a2.z,a2.w};
        float4 b = *(const float4*)&Ws[ty][i][0];
#pragma unroll
        for (int p = 0; p < 8; ++p)
            acc[p] += a[p]*b.x + a[p+1]*b.y + a[p+2]*b.z;
    }
    float bb = bias[ty];
    float s = 0.f, sq = 0.f;
#pragma unroll
    for (int h = 0; h < 2; ++h) {
        float4 v;
        v.x = acc[h*4+0] + bb; v.y = acc[h*4+1] + bb;
        v.z = acc[h*4+2] + bb; v.w = acc[h*4+3] + bb;
        s += v.x + v.y + v.z + v.w;
        sq += v.x*v.x + v.y*v.y + v.z*v.z + v.w*v.w;
        *(float4*)(out + ((size_t)n*8 + ty)*LL + l0 + tx*8 + h*4) = v;
    }
    reds[ty][tx] = s;
    redq[ty][tx] = sq;
    __syncthreads();
    if (t < 8) {
        float ss = 0.f, qq = 0.f;
#pragma unroll
        for (int x = 0; x < 32; ++x) { ss += reds[t][x]; qq += redq[t][x]; }
        part[((size_t)t * 512 + bid) * 2] = ss;
        part[((size_t)t * 512 + bid) * 2 + 1] = qq;
    }
}

// ---------------- linear 4096x4096 v4: 128x128 tile, BK=16, 8x8 micro, z=16, no prefetch ----------------
__global__ __launch_bounds__(256) void k_lin(const float* __restrict__ A, const float* __restrict__ B,
                                             float* __restrict__ part) {
    __shared__ __align__(16) float As[16][132];
    __shared__ __align__(16) float Bs[16][132];
    const int t = threadIdx.x;
    const int bid = blockIdx.x;
    const int xcd = bid & 7, j = bid >> 3;
    const int z = j >> 3;
    const int m0 = ((j >> 2) & 1) * 128;
    const int f0 = (xcd * 4 + (j & 3)) * 128;
    const int k0base = z * 256;
    const int sar = t & 127, saq = t >> 7;
    const int sbr = t >> 4, sbq = t & 15;
    const int mq = (t & 15) * 4, fq = (t >> 4) * 4;

    float acc[8][8];
#pragma unroll
    for (int i = 0; i < 8; ++i)
#pragma unroll
        for (int q = 0; q < 8; ++q) acc[i][q] = 0.f;

    for (int it = 0; it < 16; ++it) {
        const int k0 = k0base + it * 16;
        {
            const float* pA = A + (size_t)(m0 + sar) * 4096 + k0 + saq * 8;
            float4 a0 = *(const float4*)(pA);
            float4 a1 = *(const float4*)(pA + 4);
            const float* pB = B + (size_t)(k0 + sbr) * 4096 + f0 + sbq * 8;
            float4 b0 = *(const float4*)(pB);
            float4 b1 = *(const float4*)(pB + 4);
            As[saq*8+0][sar] = a0.x; As[saq*8+1][sar] = a0.y; As[saq*8+2][sar] = a0.z; As[saq*8+3][sar] = a0.w;
            As[saq*8+4][sar] = a1.x; As[saq*8+5][sar] = a1.y; As[saq*8+6][sar] = a1.z; As[saq*8+7][sar] = a1.w;
            *(float4*)&Bs[sbr][sbq*8] = b0;
            *(float4*)&Bs[sbr][sbq*8+4] = b1;
        }
        __syncthreads();
#pragma unroll
        for (int kk = 0; kk < 16; ++kk) {
            float4 a0 = *(const float4*)&As[kk][mq];
            float4 a1 = *(const float4*)&As[kk][mq + 64];
            float4 b0 = *(const float4*)&Bs[kk][fq];
            float4 b1 = *(const float4*)&Bs[kk][fq + 64];
            float av[8] = {a0.x,a0.y,a0.z,a0.w,a1.x,a1.y,a1.z,a1.w};
            float bv[8] = {b0.x,b0.y,b0.z,b0.w,b1.x,b1.y,b1.z,b1.w};
#pragma unroll
            for (int i = 0; i < 8; ++i)
#pragma unroll
                for (int q = 0; q < 8; ++q) acc[i][q] += av[i] * bv[q];
        }
        __syncthreads();
    }

#pragma unroll
    for (int i = 0; i < 8; ++i) {
        int m = m0 + mq + (i & 3) + (i >> 2) * 64;
        float4 v0 = {acc[i][0], acc[i][1], acc[i][2], acc[i][3]};
        float4 v1 = {acc[i][4], acc[i][5], acc[i][6], acc[i][7]};
        *(float4*)(part + ((size_t)z * 256 + m) * 4096 + f0 + fq) = v0;
        *(float4*)(part + ((size_t)z * 256 + m) * 4096 + f0 + fq + 64) = v1;
    }
}

// sum 16 K-partials + bias + lrelu
__global__ __launch_bounds__(256) void k_linred(const float* __restrict__ part, const float* __restrict__ bias,
        float* __restrict__ out) {
    int i4 = blockIdx.x*256 + threadIdx.x;   // < 262144
    int i = i4 << 2;
    int f = i & 4095;
    float4 s = *(const float4*)(bias + f);
#pragma unroll
    for (int zz = 0; zz < 16; ++zz) {
        float4 p = ((const float4*)(part + (size_t)zz * 1048576))[i4];
        s.x += p.x; s.y += p.y; s.z += p.z; s.w += p.w;
    }
    float4 r;
    r.x = lrelu(s.x); r.y = lrelu(s.y); r.z = lrelu(s.z); r.w = lrelu(s.w);
    ((float4*)out)[i4] = r;
}

// ---------------- heads: [4096x512 | 4096x256], split-K (16), no prefetch ----------------
__global__ __launch_bounds__(256) void k_heads(const float* __restrict__ A, const float* __restrict__ CW,
        const float* __restrict__ SW, float* __restrict__ part) {
    __shared__ __align__(16) float As[32][36];
    __shared__ __align__(16) float Bs[32][132];
    const int t = threadIdx.x;
    const int m0 = blockIdx.x * 32, f0 = blockIdx.y * 128, z = blockIdx.z;
    const float* B; int ldb, fb;
    if (f0 < 512) { B = CW; ldb = 512; fb = f0; } else { B = SW; ldb = 256; fb = f0 - 512; }
    const int tm = t & 7, tf = t >> 3;
    const int mi = t >> 3, kq = t & 7;
    float acc[4][4];
#pragma unroll
    for (int pm = 0; pm < 4; ++pm)
#pragma unroll
        for (int pf = 0; pf < 4; ++pf) acc[pm][pf] = 0.f;
    for (int k0 = z * 256; k0 < z * 256 + 256; k0 += 32) {
        float4 av = *(const float4*)(A + (size_t)(m0 + mi) * 4096 + k0 + kq * 4);
        As[kq*4+0][mi] = av.x; As[kq*4+1][mi] = av.y; As[kq*4+2][mi] = av.z; As[kq*4+3][mi] = av.w;
#pragma unroll
        for (int pass = 0; pass < 4; ++pass) {
            int fi = pass * 32 + kq * 4;
            *(float4*)&Bs[mi][fi] = *(const float4*)(B + (size_t)(k0 + mi) * ldb + fb + fi);
        }
        __syncthreads();
#pragma unroll 8
        for (int kk = 0; kk < 32; ++kk) {
            float4 a = *(const float4*)&As[kk][tm * 4];
            float4 b = *(const float4*)&Bs[kk][tf * 4];
            float avv[4] = {a.x,a.y,a.z,a.w};
            float bvv[4] = {b.x,b.y,b.z,b.w};
#pragma unroll
            for (int pm = 0; pm < 4; ++pm)
#pragma unroll
                for (int pf = 0; pf < 4; ++pf) acc[pm][pf] += avv[pm]*bvv[pf];
        }
        __syncthreads();
    }
#pragma unroll
    for (int pm = 0; pm < 4; ++pm) {
        float4 v = {acc[pm][0], acc[pm][1], acc[pm][2], acc[pm][3]};
        *(float4*)(part + ((size_t)z * 256 + m0 + tm * 4 + pm) * 768 + f0 + tf * 4) = v;
    }
}

// ---------------- assemble (fused headred) + gumbel softmax(hard) ----------------
__global__ __launch_bounds__(256) void k_assemble(const float* __restrict__ part, const float* __restrict__ cb,
        const float* __restrict__ sb, const float* __restrict__ gum, float* __restrict__ out) {
    __shared__ float buf[768];
    const int n = blockIdx.x;
    const int t = threadIdx.x;
#pragma unroll
    for (int rep = 0; rep < 3; ++rep) {
        int f = rep * 256 + t;
        float s = 0.f;
#pragma unroll
        for (int ks = 0; ks < 16; ++ks) s += part[((size_t)(ks * 256 + n)) * 768 + f];
        s += (f < 512) ? cb[f] : sb[f - 512];
        buf[f] = s;
    }
    __syncthreads();
    if (t >= 128) return;
    const int b = t;
    const float* cp = buf;
    const float* sp = buf + 512;
    float sl0 = sp[2*b], sl1 = sp[2*b+1];
    int s = sl1 > sl0 ? 1 : 0;
    int prevb = 0;
    if (b > 0) prevb = (sp[2*b-1] > sp[2*b-2]) ? 1 : 0;
    bool body = (s == 1) && (b < 127);
    bool tail = ((s == 1) && (b == 127)) || ((s == 0) && (prevb == 1));
    float c0a = cp[4*b], c0b = cp[4*b+1], c1a = cp[4*b+2], c1b = cp[4*b+3];
    bool cA = c0b > c0a, cB = c1b > c1a;
    float rows[4][3];
    if (body || tail)      { rows[0][0]=sl0; rows[0][1]=0.f; rows[0][2]=sl1; }
    else if (cA)           { rows[0][0]=c0a; rows[0][1]=c0b; rows[0][2]=0.f; }
    else                   { rows[0][0]=1.f; rows[0][1]=0.f; rows[0][2]=0.f; }
    if (body)              { rows[1][0]=0.f; rows[1][1]=0.f; rows[1][2]=1.f; }
    else                   { rows[1][0]=1.f; rows[1][1]=0.f; rows[1][2]=0.f; }
    if (body)              { rows[2][0]=0.f; rows[2][1]=0.f; rows[2][2]=1.f; }
    else if (cB)           { rows[2][0]=c1a; rows[2][1]=c1b; rows[2][2]=0.f; }
    else                   { rows[2][0]=1.f; rows[2][1]=0.f; rows[2][2]=0.f; }
    rows[3][0]=rows[1][0]; rows[3][1]=rows[1][1]; rows[3][2]=rows[1][2];
#pragma unroll
    for (int r = 0; r < 4; ++r) {
        int l = 4*b + r;
        const float* u = gum + ((size_t)n*512 + l)*3;
        float g0 = -logf(-logf(u[0]+1e-10f)+1e-10f);
        float g1 = -logf(-logf(u[1]+1e-10f)+1e-10f);
        float g2 = -logf(-logf(u[2]+1e-10f)+1e-10f);
        float t0 = rows[r][0]+g0, t1 = rows[r][1]+g1, t2 = rows[r][2]+g2;
        int am = 0; float mv = t0;
        if (t1 > mv) { am = 1; mv = t1; }
        if (t2 > mv) { am = 2; mv = t2; }
        float e0 = expf(t0-mv), e1 = expf(t1-mv), e2 = expf(t2-mv);
        float ssum = e0+e1+e2;
        float y0 = e0/ssum, y1 = e1/ssum, y2 = e2/ssum;
        float* o = out + ((size_t)n*512 + l)*3;
        o[0] = ((am==0?1.f:0.f) + y0) - y0;
        o[1] = ((am==1?1.f:0.f) + y1) - y1;
        o[2] = ((am==2?1.f:0.f) + y2) - y2;
    }
}

extern "C" void kernel_launch(void* const* d_in, const int* in_sizes, int n_in,
                              void* d_out, int out_size, void* d_ws, size_t ws_size,
                              hipStream_t stream) {
    const float* noise   = (const float*)d_in[0];
    const float* cond    = (const float*)d_in[1];
    const float* gumbel  = (const float*)d_in[2];
    const float* ext_w1  = (const float*)d_in[3];
    const float* ext_b1  = (const float*)d_in[4];
    const float* ext_w2  = (const float*)d_in[5];
    const float* ext_b2  = (const float*)d_in[6];
    const float* ext_bng = (const float*)d_in[7];
    const float* ext_bnb = (const float*)d_in[8];
    const float* m_w1    = (const float*)d_in[9];
    const float* m_b1    = (const float*)d_in[10];
    const float* m_w2    = (const float*)d_in[11];
    const float* m_b2    = (const float*)d_in[12];
    const float* m_bng   = (const float*)d_in[13];
    const float* m_bnb   = (const float*)d_in[14];
    const float* lin_w   = (const float*)d_in[15];
    const float* lin_b   = (const float*)d_in[16];
    const float* circ_w  = (const float*)d_in[17];
    const float* circ_b  = (const float*)d_in[18];
    const float* slid_w  = (const float*)d_in[19];
    const float* slid_b  = (const float*)d_in[20];

    float* genout  = (float*)d_out;                       // [256][512][3]
    float* condout = (float*)d_out + 256*512*3;           // [256][16][512]

    float* w     = (float*)d_ws;
    float* ws0   = w;                  // 16,777,216 floats: conv1 out / mconv1 partials / k_lin partials
    float* y2    = ws0 + 16777216;     // 2097152 (h2 raw / flat_in)
    float* posb  = y2 + 2097152;       // 65536
    float* pc    = posb + 65536;       // 16384  (posconv table [32][512])
    float* flatB = pc + 16384;         // 1048576
    float* partH = flatB + 1048576;    // 3145728 (heads partials z=16)
    float* statA = partH + 3145728;    // 16384 (conv2 BN partials: 16ch x 512 x 2)
    float* ssA   = statA + 16384;      // 64
    float* statB = ssA + 64;           // 8192 (mconv2 BN partials: 8ch x 512 x 2)
    float* ssB   = statB + 8192;       // 64

    k_pos<<<256, 256, 0, stream>>>(posb);
    k_posconv<<<512, 256, 0, stream>>>(posb, m_w1, m_b1, pc);
    k_conv1<<<1024, 256, 0, stream>>>(cond, ext_w1, ws0);
    k_conv2<<<512, 256, 0, stream>>>(ws0, ext_b1, ext_w2, ext_b2, y2, statA);
    k_bnfinal<<<16, 256, 0, stream>>>(statA, ext_bng, ext_bnb, 16, 512, ssA);
    k_bnapply<<<2048, 256, 0, stream>>>(y2, ssA, 16, condout, 0, 524288);
    k_mconv1<<<1024, 256, 0, stream>>>(condout, noise, pc, m_w1, ws0, ws0 + 4194304);
    k_mconv2<<<512, 256, 0, stream>>>(ws0, ws0 + 4194304, m_w2, m_b2, y2, statB);
    k_bnfinal<<<8, 256, 0, stream>>>(statB, m_bng, m_bnb, 8, 512, ssB);
    k_bnapply<<<1024, 256, 0, stream>>>(y2, ssB, 8, y2, 1, 262144);
    k_lin<<<1024, 256, 0, stream>>>(y2, lin_w, ws0);
    k_linred<<<1024, 256, 0, stream>>>(ws0, lin_b, flatB);
    k_heads<<<dim3(8,6,16), 256, 0, stream>>>(flatB, circ_w, slid_w, partH);
    k_assemble<<<256, 256, 0, stream>>>(partH, circ_b, slid_b, gumbel, genout);
}